// Round 10
// baseline (1864.955 us; speedup 1.0000x reference)
//
#include <hip/hip_runtime.h>

#define L_LAYERS 10
#define NN 10000
#define EE 160000

typedef unsigned short ushort_t;
typedef unsigned int uint_t;
typedef __attribute__((ext_vector_type(8))) short bf16x8;
typedef __attribute__((ext_vector_type(4))) float floatx4;

__device__ __forceinline__ ushort_t f2b(float f) {
  uint_t u = __float_as_uint(f);
  u += 0x7FFFu + ((u >> 16) & 1u);
  return (ushort_t)(u >> 16);
}
__device__ __forceinline__ uint_t pk2(float lo, float hi) {
  uint_t ul = __float_as_uint(lo), uh = __float_as_uint(hi);
  ul += 0x7FFFu + ((ul >> 16) & 1u);
  uh += 0x7FFFu + ((uh >> 16) & 1u);
  return (ul >> 16) | (uh & 0xFFFF0000u);
}
__device__ __forceinline__ float gelu_exact(float x) {
  return 0.5f * x * (1.0f + erff(x * 0.7071067811865475f));
}
// tanh-form GELU: x * sigmoid(1.5957691*(x + 0.044715 x^3))
__device__ __forceinline__ float gelu_fast(float x) {
  float x2 = x * x;
  float inner = fmaf(0.044715f * x2, x, x);
  float E = __expf(-1.5957691216f * inner);
  float R = __builtin_amdgcn_rcpf(1.0f + E);
  return x * R;
}
template <int CTRL>
__device__ __forceinline__ float dpp_addf(float x) {
  int y = __builtin_amdgcn_update_dpp(0, __float_as_int(x), CTRL, 0xF, 0xF, true);
  return x + __int_as_float(y);
}
__device__ __forceinline__ float row16_sum(float x) {
  x = dpp_addf<0xB1>(x);
  x = dpp_addf<0x4E>(x);
  x = dpp_addf<0x141>(x);
  x = dpp_addf<0x140>(x);
  return x;
}
#define MFMA16x32(a, b, c) __builtin_amdgcn_mfma_f32_16x16x32_bf16((a), (b), (c), 0, 0, 0)

// ---------------- weight pack: W[L][K][N] fp32 -> P[L][K/32][N][32] bf16 ----------------
__global__ __launch_bounds__(256) void k_pack_w(
    const float* __restrict__ W, ushort_t* __restrict__ P, int K, int N, int LKN)
{
  int idx = blockIdx.x * 256 + threadIdx.x;
  if (idx >= LKN) return;
  int n = idx % N;
  int t = idx / N;
  int k = t % K;
  int l = t / K;
  int ks = k >> 5, kk = k & 31;
  int Ks = K >> 5;
  P[(((size_t)((l * Ks + ks) * N + n)) << 5) + kk] = f2b(W[idx]);
}

// ---------------- encoder ----------------
__global__ __launch_bounds__(128) void k_encoder(
    const float* __restrict__ x, const float* __restrict__ W,
    const float* __restrict__ b, const float* __restrict__ g,
    const float* __restrict__ bt, float* __restrict__ h, ushort_t* __restrict__ h_bf)
{
  const int n = blockIdx.x;
  const int j = threadIdx.x;
  __shared__ float xs[7];
  __shared__ float red[4];
  if (j < 7) xs[j] = x[n * 7 + j];
  __syncthreads();
  float z = b[j];
  #pragma unroll
  for (int k = 0; k < 7; ++k) z = fmaf(xs[k], W[k * 128 + j], z);
  float sm = z, sq = z * z;
  #pragma unroll
  for (int off = 32; off > 0; off >>= 1) {
    sm += __shfl_down(sm, off);
    sq += __shfl_down(sq, off);
  }
  const int wv = j >> 6, ln = j & 63;
  if (ln == 0) { red[wv] = sm; red[2 + wv] = sq; }
  __syncthreads();
  float m = (red[0] + red[1]) * (1.0f / 128.0f);
  float var = (red[2] + red[3]) * (1.0f / 128.0f) - m * m;
  float zz = (z - m) * rsqrtf(var + 1e-5f) * g[j] + bt[j];
  float o = gelu_exact(zz);
  h[(size_t)n * 128 + j] = o;
  h_bf[(size_t)n * 128 + j] = f2b(o);
}

// ---------------- edge encoder ----------------
__global__ __launch_bounds__(256) void k_edge_enc(
    const float* __restrict__ ea, const float* __restrict__ W,
    const float* __restrict__ b, float* __restrict__ e, ushort_t* __restrict__ e_bf)
{
  const int i = blockIdx.x * 256 + threadIdx.x;
  const int eid = i >> 7, j = i & 127;
  float z = b[j];
  #pragma unroll
  for (int k = 0; k < 8; ++k) z = fmaf(ea[eid * 8 + k], W[k * 128 + j], z);
  e[i] = z;
  e_bf[i] = f2b(z);
}

// ---------------- CSR build ----------------
__global__ void k_zero_cnt(int* __restrict__ cnt) {
  int i = blockIdx.x * 256 + threadIdx.x;
  if (i < NN) cnt[i] = 0;
}
__global__ void k_count(const int* __restrict__ eidx, int* __restrict__ cnt) {
  int i = blockIdx.x * 256 + threadIdx.x;
  atomicAdd(&cnt[eidx[EE + i]], 1);
}
__global__ __launch_bounds__(256) void k_scan(
    const int* __restrict__ cnt, int* __restrict__ rowptr, int* __restrict__ fillp)
{
  __shared__ int tot[256];
  __shared__ int off[257];
  const int t = threadIdx.x;
  const int C = 40;
  int s = 0;
  int lo = t * C, hi = lo + C; if (hi > NN) hi = NN;
  for (int i = lo; i < hi; ++i) s += cnt[i];
  tot[t] = s;
  __syncthreads();
  if (t == 0) {
    int r = 0;
    for (int i = 0; i < 256; ++i) { off[i] = r; r += tot[i]; }
    off[256] = r;
  }
  __syncthreads();
  int r = off[t];
  for (int i = lo; i < hi; ++i) {
    rowptr[i] = r; fillp[i] = r;
    r += cnt[i];
  }
  if (t == 0) rowptr[NN] = off[256];
}
__global__ void k_fill(const int* __restrict__ eidx, int* __restrict__ fillp,
                       int* __restrict__ edge_of) {
  int i = blockIdx.x * 256 + threadIdx.x;
  int c = eidx[EE + i];
  int pos = atomicAdd(&fillp[c], 1);
  edge_of[pos] = i;
}

// ---------------- Hpre: per-node precompute of the h-dependent GEMM1 terms ----------------
// Hpre[n][0:256]   = h[n] @ W1a + b1   (W1 rows 0:128   -> packed ks 0-3)
// Hpre[n][256:512] = h[n] @ W1b        (W1 rows 128:256 -> packed ks 4-7)
// 32 nodes/block, 512 threads (8 waves x 64 cols of the 512-wide output).
__global__ __launch_bounds__(512) void k_hpre(
    const ushort_t* __restrict__ h_bf, const ushort_t* __restrict__ W1pk,
    const float* __restrict__ b1, float* __restrict__ Hpre, int layer)
{
  __shared__ __align__(16) ushort_t A16[32 * 136];
  const int tid = threadIdx.x;
  const int base = blockIdx.x * 32;
  const ushort_t* W1p = W1pk + (size_t)layer * (12 * 256 * 32);
  const float* b1p = b1 + layer * 256;

  // stage h_bf rows: 32 nodes x 16 chunks of 8 -> one chunk/thread
  {
    const int ei = tid >> 4, c = tid & 15;
    const int g = base + ei;
    uint4 v = {0u, 0u, 0u, 0u};
    if (g < NN) v = *(const uint4*)(h_bf + (size_t)g * 128 + c * 8);
    *(uint4*)&A16[ei * 136 + c * 8] = v;
  }
  __syncthreads();

  const int lane = tid & 63;
  const int wv = tid >> 6;        // 0..7
  const int ln15 = lane & 15;
  const int quad = lane >> 4;

  const int g0 = wv * 64;                     // output col block in [0,512)
  const int ksb = (g0 < 256) ? 0 : 4;         // W1a vs W1b packed ks base
  const int ncol = (g0 < 256) ? g0 : (g0 - 256);

  floatx4 acc[2][4];
  #pragma unroll
  for (int mi = 0; mi < 2; ++mi)
    #pragma unroll
    for (int ni = 0; ni < 4; ++ni) acc[mi][ni] = (floatx4){0.f, 0.f, 0.f, 0.f};

  for (int ks = 0; ks < 4; ++ks) {
    bf16x8 a0 = *(const bf16x8*)&A16[ln15 * 136 + ks * 32 + quad * 8];
    bf16x8 a1 = *(const bf16x8*)&A16[(16 + ln15) * 136 + ks * 32 + quad * 8];
    #pragma unroll
    for (int ni = 0; ni < 4; ++ni) {
      bf16x8 b = *(const bf16x8*)&W1p[((size_t)((ksb + ks) * 256 + ncol + ni * 16 + ln15) << 5) + quad * 8];
      acc[0][ni] = MFMA16x32(a0, b, acc[0][ni]);
      acc[1][ni] = MFMA16x32(a1, b, acc[1][ni]);
    }
  }

  #pragma unroll
  for (int ni = 0; ni < 4; ++ni) {
    int oc = g0 + ni * 16 + ln15;
    float bb = (g0 < 256) ? b1p[ncol + ni * 16 + ln15] : 0.0f;
    #pragma unroll
    for (int mi = 0; mi < 2; ++mi)
      #pragma unroll
      for (int r = 0; r < 4; ++r) {
        int row = mi * 16 + quad * 4 + r;
        int g = base + row;
        if (g < NN) Hpre[(size_t)g * 512 + oc] = acc[mi][ni][r] + bb;
      }
  }
}

// ---------------- edge MLP (MFMA): 32 edges/block, 4 waves ----------------
// GEMM1 reduced to K=128 (e @ W1c, packed ks 8-11); h-dependent terms + b1 come from Hpre gather.
__global__ __launch_bounds__(256) void k_edge_mlp_mfma(
    const float* __restrict__ Hpre, float* __restrict__ e, ushort_t* __restrict__ e_bf,
    const int* __restrict__ eidx,
    const ushort_t* __restrict__ W1pk, const ushort_t* __restrict__ W2pk,
    const float* __restrict__ g1, const float* __restrict__ bt1,
    const float* __restrict__ b2, const float* __restrict__ g2, const float* __restrict__ bt2,
    int layer)
{
  __shared__ __align__(16) ushort_t A16[32 * 136];   // e tile only
  __shared__ __align__(16) ushort_t Z16[32 * 264];
  __shared__ float red_s[32 * 4], red_q[32 * 4];
  __shared__ int s_row[32], s_col[32];

  const int tid = threadIdx.x;
  const int base = blockIdx.x * 32;
  const ushort_t* W1p = W1pk + (size_t)layer * (12 * 256 * 32);
  const ushort_t* W2p = W2pk + (size_t)layer * (8 * 128 * 32);
  const float* g1p = g1 + layer * 256;
  const float* bt1p = bt1 + layer * 256;
  const float* b2p = b2 + layer * 128;
  const float* g2p = g2 + layer * 128;
  const float* bt2p = bt2 + layer * 128;

  if (tid < 32) s_row[tid] = eidx[base + tid];
  else if (tid < 64) s_col[tid - 32] = eidx[EE + base + (tid - 32)];
  __syncthreads();

  // stage e (bf16 mirror): 32 edges x 16 chunks of 8 -> 2 chunks/thread
  #pragma unroll
  for (int i = 0; i < 2; ++i) {
    int idx = tid + i * 256;
    int ei = idx >> 4, c = idx & 15;
    *(uint4*)&A16[ei * 136 + c * 8] =
        *(const uint4*)(e_bf + (size_t)(base + ei) * 128 + c * 8);
  }
  __syncthreads();

  const int lane = tid & 63;
  const int wv = tid >> 6;
  const int ln15 = lane & 15;
  const int quad = lane >> 4;

  // ---- GEMM1 (K=128): [32x128] @ [128x256] using packed ks 8-11 ----
  floatx4 acc[2][4];
  #pragma unroll
  for (int mi = 0; mi < 2; ++mi)
    #pragma unroll
    for (int ni = 0; ni < 4; ++ni) acc[mi][ni] = (floatx4){0.f, 0.f, 0.f, 0.f};

  const int nb1 = wv * 64;
  for (int ks = 0; ks < 4; ++ks) {
    bf16x8 a0 = *(const bf16x8*)&A16[ln15 * 136 + ks * 32 + quad * 8];
    bf16x8 a1 = *(const bf16x8*)&A16[(16 + ln15) * 136 + ks * 32 + quad * 8];
    #pragma unroll
    for (int ni = 0; ni < 4; ++ni) {
      bf16x8 b = *(const bf16x8*)&W1p[((size_t)((8 + ks) * 256 + nb1 + ni * 16 + ln15) << 5) + quad * 8];
      acc[0][ni] = MFMA16x32(a0, b, acc[0][ni]);
      acc[1][ni] = MFMA16x32(a1, b, acc[1][ni]);
    }
  }

  // add Hpre gather: acc += Hrow[s_row][col] + Hcol[s_col][col] (b1 already folded in)
  #pragma unroll
  for (int mi = 0; mi < 2; ++mi)
    #pragma unroll
    for (int r = 0; r < 4; ++r) {
      int row = mi * 16 + quad * 4 + r;
      const float* pr = Hpre + (size_t)s_row[row] * 512;
      const float* pc = Hpre + (size_t)s_col[row] * 512 + 256;
      #pragma unroll
      for (int ni = 0; ni < 4; ++ni) {
        int col = nb1 + ni * 16 + ln15;
        acc[mi][ni][r] += pr[col] + pc[col];
      }
    }

  // LN1 partials
  #pragma unroll
  for (int mi = 0; mi < 2; ++mi)
    #pragma unroll
    for (int r = 0; r < 4; ++r) {
      float v = 0.f, u = 0.f;
      #pragma unroll
      for (int ni = 0; ni < 4; ++ni) { float x = acc[mi][ni][r]; v += x; u += x * x; }
      v = row16_sum(v); u = row16_sum(u);
      if (ln15 == 0) {
        int row = mi * 16 + quad * 4 + r;
        red_s[row * 4 + wv] = v; red_q[row * 4 + wv] = u;
      }
    }
  __syncthreads();

  float mrow[2][4], rrow[2][4];
  #pragma unroll
  for (int mi = 0; mi < 2; ++mi)
    #pragma unroll
    for (int r = 0; r < 4; ++r) {
      int row = mi * 16 + quad * 4 + r;
      float S = red_s[row * 4] + red_s[row * 4 + 1] + red_s[row * 4 + 2] + red_s[row * 4 + 3];
      float Q = red_q[row * 4] + red_q[row * 4 + 1] + red_q[row * 4 + 2] + red_q[row * 4 + 3];
      float m = S * (1.f / 256.f);
      float var = Q * (1.f / 256.f) - m * m;
      mrow[mi][r] = m; rrow[mi][r] = rsqrtf(var + 1e-5f);
    }
  #pragma unroll
  for (int ni = 0; ni < 4; ++ni) {
    int col = nb1 + ni * 16 + ln15;
    float gg = g1p[col], bb = bt1p[col];
    #pragma unroll
    for (int mi = 0; mi < 2; ++mi)
      #pragma unroll
      for (int r = 0; r < 4; ++r) {
        int row = mi * 16 + quad * 4 + r;
        float z = (acc[mi][ni][r] - mrow[mi][r]) * rrow[mi][r] * gg + bb;
        Z16[row * 264 + col] = f2b(gelu_fast(z));
      }
  }
  __syncthreads();

  // ---- GEMM2: [32x256] @ [256x128], ks ping-pong B prefetch ----
  floatx4 c2[2][2];
  #pragma unroll
  for (int mi = 0; mi < 2; ++mi)
    #pragma unroll
    for (int ni = 0; ni < 2; ++ni) c2[mi][ni] = (floatx4){0.f, 0.f, 0.f, 0.f};

  const int nb2 = wv * 32;
  {
    const ushort_t* Wf = W2p + ((size_t)(nb2 + ln15) << 5) + quad * 8;
    bf16x8 bA[2], bB[2];
    #pragma unroll
    for (int ni = 0; ni < 2; ++ni) bA[ni] = *(const bf16x8*)(Wf + (size_t)ni * (16 << 5));
    #pragma unroll
    for (int ks = 0; ks < 8; ks += 2) {
      #pragma unroll
      for (int ni = 0; ni < 2; ++ni)
        bB[ni] = *(const bf16x8*)(Wf + (size_t)(ks + 1) * (128 << 5) + (size_t)ni * (16 << 5));
      {
        bf16x8 a0 = *(const bf16x8*)&Z16[ln15 * 264 + ks * 32 + quad * 8];
        bf16x8 a1 = *(const bf16x8*)&Z16[(16 + ln15) * 264 + ks * 32 + quad * 8];
        #pragma unroll
        for (int ni = 0; ni < 2; ++ni) {
          c2[0][ni] = MFMA16x32(a0, bA[ni], c2[0][ni]);
          c2[1][ni] = MFMA16x32(a1, bA[ni], c2[1][ni]);
        }
      }
      if (ks + 2 < 8) {
        #pragma unroll
        for (int ni = 0; ni < 2; ++ni)
          bA[ni] = *(const bf16x8*)(Wf + (size_t)(ks + 2) * (128 << 5) + (size_t)ni * (16 << 5));
      }
      {
        bf16x8 a0 = *(const bf16x8*)&Z16[ln15 * 264 + (ks + 1) * 32 + quad * 8];
        bf16x8 a1 = *(const bf16x8*)&Z16[(16 + ln15) * 264 + (ks + 1) * 32 + quad * 8];
        #pragma unroll
        for (int ni = 0; ni < 2; ++ni) {
          c2[0][ni] = MFMA16x32(a0, bB[ni], c2[0][ni]);
          c2[1][ni] = MFMA16x32(a1, bB[ni], c2[1][ni]);
        }
      }
    }
  }

  #pragma unroll
  for (int ni = 0; ni < 2; ++ni) {
    float bb = b2p[nb2 + ni * 16 + ln15];
    #pragma unroll
    for (int mi = 0; mi < 2; ++mi)
      #pragma unroll
      for (int r = 0; r < 4; ++r) c2[mi][ni][r] += bb;
  }
  #pragma unroll
  for (int mi = 0; mi < 2; ++mi)
    #pragma unroll
    for (int r = 0; r < 4; ++r) {
      float v = 0.f, u = 0.f;
      #pragma unroll
      for (int ni = 0; ni < 2; ++ni) { float x = c2[mi][ni][r]; v += x; u += x * x; }
      v = row16_sum(v); u = row16_sum(u);
      if (ln15 == 0) {
        int row = mi * 16 + quad * 4 + r;
        red_s[row * 4 + wv] = v; red_q[row * 4 + wv] = u;
      }
    }
  __syncthreads();

  #pragma unroll
  for (int mi = 0; mi < 2; ++mi)
    #pragma unroll
    for (int r = 0; r < 4; ++r) {
      int row = mi * 16 + quad * 4 + r;
      float S = red_s[row * 4] + red_s[row * 4 + 1] + red_s[row * 4 + 2] + red_s[row * 4 + 3];
      float Q = red_q[row * 4] + red_q[row * 4 + 1] + red_q[row * 4 + 2] + red_q[row * 4 + 3];
      float m = S * (1.f / 128.f);
      float var = Q * (1.f / 128.f) - m * m;
      mrow[mi][r] = m; rrow[mi][r] = rsqrtf(var + 1e-5f);
    }
  #pragma unroll
  for (int ni = 0; ni < 2; ++ni) {
    int col = nb2 + ni * 16 + ln15;
    float gg = g2p[col], bb = bt2p[col];
    #pragma unroll
    for (int mi = 0; mi < 2; ++mi)
      #pragma unroll
      for (int r = 0; r < 4; ++r) {
        int row = mi * 16 + quad * 4 + r;
        float z = (c2[mi][ni][r] - mrow[mi][r]) * rrow[mi][r] * gg + bb;
        size_t gi = (size_t)(base + row) * 128 + col;
        float nv = e[gi] + z;
        e[gi] = nv;
        e_bf[gi] = f2b(nv);
      }
  }
}

// ---------------- node MLP (MFMA, fused scatter-mean): 32 nodes/block ----------------
__global__ __launch_bounds__(256) void k_node_mlp_mfma(
    float* __restrict__ h, ushort_t* __restrict__ h_bf, const ushort_t* __restrict__ e_bf,
    const int* __restrict__ rowptr, const int* __restrict__ edge_of,
    const ushort_t* __restrict__ W1pk, const ushort_t* __restrict__ W2pk,
    const float* __restrict__ b1, const float* __restrict__ g1, const float* __restrict__ bt1,
    const float* __restrict__ b2, const float* __restrict__ g2, const float* __restrict__ bt2,
    int layer)
{
  __shared__ __align__(16) ushort_t A16[32 * 264];
  __shared__ float red_s[32 * 4], red_q[32 * 4];
  ushort_t* Z16 = A16;

  const int tid = threadIdx.x;
  const int base = blockIdx.x * 32;
  const ushort_t* W1p = W1pk + (size_t)layer * (8 * 256 * 32);
  const ushort_t* W2p = W2pk + (size_t)layer * (8 * 128 * 32);
  const float* b1p = b1 + layer * 256;
  const float* g1p = g1 + layer * 256;
  const float* bt1p = bt1 + layer * 256;
  const float* b2p = b2 + layer * 128;
  const float* g2p = g2 + layer * 128;
  const float* bt2p = bt2 + layer * 128;

  // staging: 8 threads/node; seg owns 16 cols of h and 16 cols of agg
  {
    const int node = tid >> 3, seg = tid & 7;
    const int g = base + node;
    if (g < NN) {
      *(uint4*)&A16[node * 264 + seg * 16] =
          *(const uint4*)(h_bf + (size_t)g * 128 + seg * 16);
      *(uint4*)&A16[node * 264 + seg * 16 + 8] =
          *(const uint4*)(h_bf + (size_t)g * 128 + seg * 16 + 8);
      const int s = rowptr[g], en = rowptr[g + 1];
      float a[16];
      #pragma unroll
      for (int q = 0; q < 16; ++q) a[q] = 0.f;
      for (int it = s; it < en; ++it) {
        const ushort_t* src = e_bf + (size_t)edge_of[it] * 128 + seg * 16;
        uint4 v0 = *(const uint4*)src;
        uint4 v1 = *(const uint4*)(src + 8);
        a[0] += __uint_as_float(v0.x << 16); a[1] += __uint_as_float(v0.x & 0xFFFF0000u);
        a[2] += __uint_as_float(v0.y << 16); a[3] += __uint_as_float(v0.y & 0xFFFF0000u);
        a[4] += __uint_as_float(v0.z << 16); a[5] += __uint_as_float(v0.z & 0xFFFF0000u);
        a[6] += __uint_as_float(v0.w << 16); a[7] += __uint_as_float(v0.w & 0xFFFF0000u);
        a[8]  += __uint_as_float(v1.x << 16); a[9]  += __uint_as_float(v1.x & 0xFFFF0000u);
        a[10] += __uint_as_float(v1.y << 16); a[11] += __uint_as_float(v1.y & 0xFFFF0000u);
        a[12] += __uint_as_float(v1.z << 16); a[13] += __uint_as_float(v1.z & 0xFFFF0000u);
        a[14] += __uint_as_float(v1.w << 16); a[15] += __uint_as_float(v1.w & 0xFFFF0000u);
      }
      int c = en - s;
      float inv = 1.0f / (float)(c > 0 ? c : 1);
      uint4 p0, p1;
      p0.x = pk2(a[0] * inv, a[1] * inv);  p0.y = pk2(a[2] * inv, a[3] * inv);
      p0.z = pk2(a[4] * inv, a[5] * inv);  p0.w = pk2(a[6] * inv, a[7] * inv);
      p1.x = pk2(a[8] * inv, a[9] * inv);  p1.y = pk2(a[10] * inv, a[11] * inv);
      p1.z = pk2(a[12] * inv, a[13] * inv); p1.w = pk2(a[14] * inv, a[15] * inv);
      *(uint4*)&A16[node * 264 + 128 + seg * 16] = p0;
      *(uint4*)&A16[node * 264 + 128 + seg * 16 + 8] = p1;
    } else {
      uint4 zz = {0u, 0u, 0u, 0u};
      *(uint4*)&A16[node * 264 + seg * 16] = zz;
      *(uint4*)&A16[node * 264 + seg * 16 + 8] = zz;
      *(uint4*)&A16[node * 264 + 128 + seg * 16] = zz;
      *(uint4*)&A16[node * 264 + 128 + seg * 16 + 8] = zz;
    }
  }
  __syncthreads();

  const int lane = tid & 63;
  const int wv = tid >> 6;
  const int ln15 = lane & 15;
  const int quad = lane >> 4;

  // ---- GEMM1: [32x256] @ [256x256]; wave: 2 m-tiles x 4 n-tiles ----
  floatx4 acc[2][4];
  #pragma unroll
  for (int mi = 0; mi < 2; ++mi)
    #pragma unroll
    for (int ni = 0; ni < 4; ++ni) acc[mi][ni] = (floatx4){0.f, 0.f, 0.f, 0.f};

  const int nb1 = wv * 64;
  for (int ks = 0; ks < 8; ++ks) {
    bf16x8 a0 = *(const bf16x8*)&A16[ln15 * 264 + ks * 32 + quad * 8];
    bf16x8 a1 = *(const bf16x8*)&A16[(16 + ln15) * 264 + ks * 32 + quad * 8];
    #pragma unroll
    for (int ni = 0; ni < 4; ++ni) {
      bf16x8 b = *(const bf16x8*)&W1p[((size_t)(ks * 256 + nb1 + ni * 16 + ln15) << 5) + quad * 8];
      acc[0][ni] = MFMA16x32(a0, b, acc[0][ni]);
      acc[1][ni] = MFMA16x32(a1, b, acc[1][ni]);
    }
  }

  #pragma unroll
  for (int ni = 0; ni < 4; ++ni) {
    float bb = b1p[nb1 + ni * 16 + ln15];
    #pragma unroll
    for (int mi = 0; mi < 2; ++mi)
      #pragma unroll
      for (int r = 0; r < 4; ++r) acc[mi][ni][r] += bb;
  }
  #pragma unroll
  for (int mi = 0; mi < 2; ++mi)
    #pragma unroll
    for (int r = 0; r < 4; ++r) {
      float v = 0.f, u = 0.f;
      #pragma unroll
      for (int ni = 0; ni < 4; ++ni) { float x = acc[mi][ni][r]; v += x; u += x * x; }
      v = row16_sum(v); u = row16_sum(u);
      if (ln15 == 0) {
        int row = mi * 16 + quad * 4 + r;
        red_s[row * 4 + wv] = v; red_q[row * 4 + wv] = u;
      }
    }
  __syncthreads();

  float mrow[2][4], rrow[2][4];
  #pragma unroll
  for (int mi = 0; mi < 2; ++mi)
    #pragma unroll
    for (int r = 0; r < 4; ++r) {
      int row = mi * 16 + quad * 4 + r;
      float S = red_s[row * 4] + red_s[row * 4 + 1] + red_s[row * 4 + 2] + red_s[row * 4 + 3];
      float Q = red_q[row * 4] + red_q[row * 4 + 1] + red_q[row * 4 + 2] + red_q[row * 4 + 3];
      float m = S * (1.f / 256.f);
      float var = Q * (1.f / 256.f) - m * m;
      mrow[mi][r] = m; rrow[mi][r] = rsqrtf(var + 1e-5f);
    }
  #pragma unroll
  for (int ni = 0; ni < 4; ++ni) {
    int col = nb1 + ni * 16 + ln15;
    float gg = g1p[col], bb = bt1p[col];
    #pragma unroll
    for (int mi = 0; mi < 2; ++mi)
      #pragma unroll
      for (int r = 0; r < 4; ++r) {
        int row = mi * 16 + quad * 4 + r;
        float z = (acc[mi][ni][r] - mrow[mi][r]) * rrow[mi][r] * gg + bb;
        Z16[row * 264 + col] = f2b(gelu_fast(z));
      }
  }
  __syncthreads();

  // ---- GEMM2: [32x256] @ [256x128]; wave: 2 m-tiles x 2 n-tiles ----
  floatx4 c2[2][2];
  #pragma unroll
  for (int mi = 0; mi < 2; ++mi)
    #pragma unroll
    for (int ni = 0; ni < 2; ++ni) c2[mi][ni] = (floatx4){0.f, 0.f, 0.f, 0.f};

  const int nb2 = wv * 32;
  for (int ks = 0; ks < 8; ++ks) {
    bf16x8 a0 = *(const bf16x8*)&Z16[ln15 * 264 + ks * 32 + quad * 8];
    bf16x8 a1 = *(const bf16x8*)&Z16[(16 + ln15) * 264 + ks * 32 + quad * 8];
    #pragma unroll
    for (int ni = 0; ni < 2; ++ni) {
      bf16x8 b = *(const bf16x8*)&W2p[((size_t)(ks * 128 + nb2 + ni * 16 + ln15) << 5) + quad * 8];
      c2[0][ni] = MFMA16x32(a0, b, c2[0][ni]);
      c2[1][ni] = MFMA16x32(a1, b, c2[1][ni]);
    }
  }

  #pragma unroll
  for (int ni = 0; ni < 2; ++ni) {
    float bb = b2p[nb2 + ni * 16 + ln15];
    #pragma unroll
    for (int mi = 0; mi < 2; ++mi)
      #pragma unroll
      for (int r = 0; r < 4; ++r) c2[mi][ni][r] += bb;
  }
  #pragma unroll
  for (int mi = 0; mi < 2; ++mi)
    #pragma unroll
    for (int r = 0; r < 4; ++r) {
      float v = 0.f, u = 0.f;
      #pragma unroll
      for (int ni = 0; ni < 2; ++ni) { float x = c2[mi][ni][r]; v += x; u += x * x; }
      v = row16_sum(v); u = row16_sum(u);
      if (ln15 == 0) {
        int row = mi * 16 + quad * 4 + r;
        red_s[row * 4 + wv] = v; red_q[row * 4 + wv] = u;
      }
    }
  __syncthreads();

  #pragma unroll
  for (int mi = 0; mi < 2; ++mi)
    #pragma unroll
    for (int r = 0; r < 4; ++r) {
      int row = mi * 16 + quad * 4 + r;
      float S = red_s[row * 4] + red_s[row * 4 + 1] + red_s[row * 4 + 2] + red_s[row * 4 + 3];
      float Q = red_q[row * 4] + red_q[row * 4 + 1] + red_q[row * 4 + 2] + red_q[row * 4 + 3];
      float m = S * (1.f / 128.f);
      float var = Q * (1.f / 128.f) - m * m;
      mrow[mi][r] = m; rrow[mi][r] = rsqrtf(var + 1e-5f);
    }
  #pragma unroll
  for (int ni = 0; ni < 2; ++ni) {
    int col = nb2 + ni * 16 + ln15;
    float gg = g2p[col], bb = bt2p[col];
    #pragma unroll
    for (int mi = 0; mi < 2; ++mi)
      #pragma unroll
      for (int r = 0; r < 4; ++r) {
        int row = mi * 16 + quad * 4 + r;
        int g = base + row;
        if (g < NN) {
          float z = (c2[mi][ni][r] - mrow[mi][r]) * rrow[mi][r] * gg + bb;
          size_t gi = (size_t)g * 128 + col;
          float nv = h[gi] + z;
          h[gi] = nv;
          h_bf[gi] = f2b(nv);
        }
      }
  }
}

// ---------------- decoder ----------------
__global__ __launch_bounds__(128) void k_decoder(
    const float* __restrict__ h, const float* __restrict__ W1,
    const float* __restrict__ b1, const float* __restrict__ W2,
    const float* __restrict__ b2, float* __restrict__ out)
{
  const int n = blockIdx.x;
  const int j = threadIdx.x;
  __shared__ float hs[128];
  __shared__ float z1s[128];
  hs[j] = h[(size_t)n * 128 + j];
  __syncthreads();
  float z = b1[j];
  for (int k = 0; k < 128; ++k) z = fmaf(hs[k], W1[k * 128 + j], z);
  z1s[j] = gelu_exact(z);
  __syncthreads();
  if (j < 4) {
    float o = b2[j];
    for (int k = 0; k < 128; ++k) o = fmaf(z1s[k], W2[k * 4 + j], o);
    out[n * 4 + j] = o;
  }
}

static inline char* align_up(char* p, size_t a) {
  return (char*)(((uintptr_t)p + (a - 1)) & ~(uintptr_t)(a - 1));
}

extern "C" void kernel_launch(void* const* d_in, const int* in_sizes, int n_in,
                              void* d_out, int out_size, void* d_ws, size_t ws_size,
                              hipStream_t stream) {
  const float* x     = (const float*)d_in[0];
  const int*   eidx  = (const int*)d_in[1];
  const float* ea    = (const float*)d_in[2];
  const float* encW  = (const float*)d_in[3];
  const float* encb  = (const float*)d_in[4];
  const float* encg  = (const float*)d_in[5];
  const float* encbt = (const float*)d_in[6];
  const float* eencW = (const float*)d_in[7];
  const float* eencb = (const float*)d_in[8];
  const float* eW1   = (const float*)d_in[9];
  const float* eb1   = (const float*)d_in[10];
  const float* eg1   = (const float*)d_in[11];
  const float* ebt1  = (const float*)d_in[12];
  const float* eW2   = (const float*)d_in[13];
  const float* eb2   = (const float*)d_in[14];
  const float* eg2   = (const float*)d_in[15];
  const float* ebt2  = (const float*)d_in[16];
  const float* nW1   = (const float*)d_in[17];
  const float* nb1   = (const float*)d_in[18];
  const float* ng1   = (const float*)d_in[19];
  const float* nbt1  = (const float*)d_in[20];
  const float* nW2   = (const float*)d_in[21];
  const float* nb2   = (const float*)d_in[22];
  const float* ng2   = (const float*)d_in[23];
  const float* nbt2  = (const float*)d_in[24];
  const float* dW1   = (const float*)d_in[25];
  const float* db1   = (const float*)d_in[26];
  const float* dW2   = (const float*)d_in[27];
  const float* db2   = (const float*)d_in[28];
  float* out = (float*)d_out;

  char* p = (char*)d_ws;
  float* h   = (float*)p; p += (size_t)NN * 128 * 4;
  float* e   = (float*)p; p += (size_t)EE * 128 * 4;
  int* cnt     = (int*)p; p += (size_t)NN * 4;
  int* rowptr  = (int*)p; p += (size_t)(NN + 1) * 4;
  int* fillp   = (int*)p; p += (size_t)NN * 4;
  int* edge_of = (int*)p; p += (size_t)EE * 4;
  p = align_up(p, 256);
  ushort_t* h_bf = (ushort_t*)p; p += (size_t)NN * 128 * 2;
  p = align_up(p, 256);
  ushort_t* e_bf = (ushort_t*)p; p += (size_t)EE * 128 * 2;
  p = align_up(p, 256);
  float* Hpre = (float*)p; p += (size_t)NN * 512 * 4;
  p = align_up(p, 256);
  ushort_t* eW1pk = (ushort_t*)p; p += (size_t)L_LAYERS * 12 * 256 * 32 * 2;
  p = align_up(p, 256);
  ushort_t* eW2pk = (ushort_t*)p; p += (size_t)L_LAYERS * 8 * 128 * 32 * 2;
  p = align_up(p, 256);
  ushort_t* nW1pk = (ushort_t*)p; p += (size_t)L_LAYERS * 8 * 256 * 32 * 2;
  p = align_up(p, 256);
  ushort_t* nW2pk = (ushort_t*)p; p += (size_t)L_LAYERS * 8 * 128 * 32 * 2;

  {
    int n1 = L_LAYERS * 384 * 256;
    k_pack_w<<<(n1 + 255) / 256, 256, 0, stream>>>(eW1, eW1pk, 384, 256, n1);
    int n2 = L_LAYERS * 256 * 128;
    k_pack_w<<<(n2 + 255) / 256, 256, 0, stream>>>(eW2, eW2pk, 256, 128, n2);
    int n3 = L_LAYERS * 256 * 256;
    k_pack_w<<<(n3 + 255) / 256, 256, 0, stream>>>(nW1, nW1pk, 256, 256, n3);
    int n4 = L_LAYERS * 256 * 128;
    k_pack_w<<<(n4 + 255) / 256, 256, 0, stream>>>(nW2, nW2pk, 256, 128, n4);
  }

  k_encoder<<<NN, 128, 0, stream>>>(x, encW, encb, encg, encbt, h, h_bf);
  k_edge_enc<<<(EE * 128) / 256, 256, 0, stream>>>(ea, eencW, eencb, e, e_bf);
  k_zero_cnt<<<(NN + 255) / 256, 256, 0, stream>>>(cnt);
  k_count<<<EE / 256, 256, 0, stream>>>(eidx, cnt);
  k_scan<<<1, 256, 0, stream>>>(cnt, rowptr, fillp);
  k_fill<<<EE / 256, 256, 0, stream>>>(eidx, fillp, edge_of);

  for (int l = 0; l < L_LAYERS; ++l) {
    k_hpre<<<(NN + 31) / 32, 512, 0, stream>>>(h_bf, eW1pk, eb1, Hpre, l);
    k_edge_mlp_mfma<<<EE / 32, 256, 0, stream>>>(Hpre, e, e_bf, eidx,
        eW1pk, eW2pk, eg1, ebt1, eb2, eg2, ebt2, l);
    k_node_mlp_mfma<<<(NN + 31) / 32, 256, 0, stream>>>(h, h_bf, e_bf, rowptr, edge_of,
        nW1pk, nW2pk, nb1, ng1, nbt1, nb2, ng2, nbt2, l);
  }
  k_decoder<<<NN, 128, 0, stream>>>(h, dW1, db1, dW2, db2, out);
}

// Round 11
// 1667.376 us; speedup vs baseline: 1.1185x; 1.1185x over previous
//
#include <hip/hip_runtime.h>

#define L_LAYERS 10
#define NN 10000
#define EE 160000

typedef unsigned short ushort_t;
typedef unsigned int uint_t;
typedef __attribute__((ext_vector_type(8))) short bf16x8;
typedef __attribute__((ext_vector_type(4))) float floatx4;

__device__ __forceinline__ ushort_t f2b(float f) {
  uint_t u = __float_as_uint(f);
  u += 0x7FFFu + ((u >> 16) & 1u);
  return (ushort_t)(u >> 16);
}
__device__ __forceinline__ uint_t pk2(float lo, float hi) {
  uint_t ul = __float_as_uint(lo), uh = __float_as_uint(hi);
  ul += 0x7FFFu + ((ul >> 16) & 1u);
  uh += 0x7FFFu + ((uh >> 16) & 1u);
  return (ul >> 16) | (uh & 0xFFFF0000u);
}
__device__ __forceinline__ float gelu_exact(float x) {
  return 0.5f * x * (1.0f + erff(x * 0.7071067811865475f));
}
// tanh-form GELU: x * sigmoid(1.5957691*(x + 0.044715 x^3))
__device__ __forceinline__ float gelu_fast(float x) {
  float x2 = x * x;
  float inner = fmaf(0.044715f * x2, x, x);
  float E = __expf(-1.5957691216f * inner);
  float R = __builtin_amdgcn_rcpf(1.0f + E);
  return x * R;
}
template <int CTRL>
__device__ __forceinline__ float dpp_addf(float x) {
  int y = __builtin_amdgcn_update_dpp(0, __float_as_int(x), CTRL, 0xF, 0xF, true);
  return x + __int_as_float(y);
}
__device__ __forceinline__ float row16_sum(float x) {
  x = dpp_addf<0xB1>(x);
  x = dpp_addf<0x4E>(x);
  x = dpp_addf<0x141>(x);
  x = dpp_addf<0x140>(x);
  return x;
}
#define MFMA16x32(a, b, c) __builtin_amdgcn_mfma_f32_16x16x32_bf16((a), (b), (c), 0, 0, 0)

// ---------------- weight pack: W[L][K][N] fp32 -> P[L][K/32][N][32] bf16 ----------------
__global__ __launch_bounds__(256) void k_pack_w(
    const float* __restrict__ W, ushort_t* __restrict__ P, int K, int N, int LKN)
{
  int idx = blockIdx.x * 256 + threadIdx.x;
  if (idx >= LKN) return;
  int n = idx % N;
  int t = idx / N;
  int k = t % K;
  int l = t / K;
  int ks = k >> 5, kk = k & 31;
  int Ks = K >> 5;
  P[(((size_t)((l * Ks + ks) * N + n)) << 5) + kk] = f2b(W[idx]);
}

// ---------------- encoder ----------------
__global__ __launch_bounds__(128) void k_encoder(
    const float* __restrict__ x, const float* __restrict__ W,
    const float* __restrict__ b, const float* __restrict__ g,
    const float* __restrict__ bt, float* __restrict__ h, ushort_t* __restrict__ h_bf)
{
  const int n = blockIdx.x;
  const int j = threadIdx.x;
  __shared__ float xs[7];
  __shared__ float red[4];
  if (j < 7) xs[j] = x[n * 7 + j];
  __syncthreads();
  float z = b[j];
  #pragma unroll
  for (int k = 0; k < 7; ++k) z = fmaf(xs[k], W[k * 128 + j], z);
  float sm = z, sq = z * z;
  #pragma unroll
  for (int off = 32; off > 0; off >>= 1) {
    sm += __shfl_down(sm, off);
    sq += __shfl_down(sq, off);
  }
  const int wv = j >> 6, ln = j & 63;
  if (ln == 0) { red[wv] = sm; red[2 + wv] = sq; }
  __syncthreads();
  float m = (red[0] + red[1]) * (1.0f / 128.0f);
  float var = (red[2] + red[3]) * (1.0f / 128.0f) - m * m;
  float zz = (z - m) * rsqrtf(var + 1e-5f) * g[j] + bt[j];
  float o = gelu_exact(zz);
  h[(size_t)n * 128 + j] = o;
  h_bf[(size_t)n * 128 + j] = f2b(o);
}

// ---------------- edge encoder ----------------
__global__ __launch_bounds__(256) void k_edge_enc(
    const float* __restrict__ ea, const float* __restrict__ W,
    const float* __restrict__ b, float* __restrict__ e, ushort_t* __restrict__ e_bf)
{
  const int i = blockIdx.x * 256 + threadIdx.x;
  const int eid = i >> 7, j = i & 127;
  float z = b[j];
  #pragma unroll
  for (int k = 0; k < 8; ++k) z = fmaf(ea[eid * 8 + k], W[k * 128 + j], z);
  e[i] = z;
  e_bf[i] = f2b(z);
}

// ---------------- CSR build ----------------
__global__ void k_zero_cnt(int* __restrict__ cnt) {
  int i = blockIdx.x * 256 + threadIdx.x;
  if (i < NN) cnt[i] = 0;
}
__global__ void k_count(const int* __restrict__ eidx, int* __restrict__ cnt) {
  int i = blockIdx.x * 256 + threadIdx.x;
  atomicAdd(&cnt[eidx[EE + i]], 1);
}
__global__ __launch_bounds__(256) void k_scan(
    const int* __restrict__ cnt, int* __restrict__ rowptr, int* __restrict__ fillp)
{
  __shared__ int tot[256];
  __shared__ int off[257];
  const int t = threadIdx.x;
  const int C = 40;
  int s = 0;
  int lo = t * C, hi = lo + C; if (hi > NN) hi = NN;
  for (int i = lo; i < hi; ++i) s += cnt[i];
  tot[t] = s;
  __syncthreads();
  if (t == 0) {
    int r = 0;
    for (int i = 0; i < 256; ++i) { off[i] = r; r += tot[i]; }
    off[256] = r;
  }
  __syncthreads();
  int r = off[t];
  for (int i = lo; i < hi; ++i) {
    rowptr[i] = r; fillp[i] = r;
    r += cnt[i];
  }
  if (t == 0) rowptr[NN] = off[256];
}
__global__ void k_fill(const int* __restrict__ eidx, int* __restrict__ fillp,
                       int* __restrict__ edge_of) {
  int i = blockIdx.x * 256 + threadIdx.x;
  int c = eidx[EE + i];
  int pos = atomicAdd(&fillp[c], 1);
  edge_of[pos] = i;
}

// ---------------- Hpre: per-node precompute of the h-dependent GEMM1 terms ----------------
// Stored bf16, C-fragment-permuted: Hpre[n][block*64 + ln15*4 + ni] holds
//   block<4 : (h[n] @ W1a + b1) at col block*64 + ni*16 + ln15      (packed ks 0-3)
//   block>=4: (h[n] @ W1b)      at col (block-4)*64 + ni*16 + ln15  (packed ks 4-7)
// so an edge-kernel lane reads its 4 ni values as one contiguous 8B chunk.
__global__ __launch_bounds__(512) void k_hpre(
    const ushort_t* __restrict__ h_bf, const ushort_t* __restrict__ W1pk,
    const float* __restrict__ b1, ushort_t* __restrict__ Hpre, int layer)
{
  __shared__ __align__(16) ushort_t A16[32 * 136];
  const int tid = threadIdx.x;
  const int base = blockIdx.x * 32;
  const ushort_t* W1p = W1pk + (size_t)layer * (12 * 256 * 32);
  const float* b1p = b1 + layer * 256;

  // stage h_bf rows: 32 nodes x 16 chunks of 8 -> one chunk/thread
  {
    const int ei = tid >> 4, c = tid & 15;
    const int g = base + ei;
    uint4 v = {0u, 0u, 0u, 0u};
    if (g < NN) v = *(const uint4*)(h_bf + (size_t)g * 128 + c * 8);
    *(uint4*)&A16[ei * 136 + c * 8] = v;
  }
  __syncthreads();

  const int lane = tid & 63;
  const int wv = tid >> 6;        // 0..7
  const int ln15 = lane & 15;
  const int quad = lane >> 4;

  const int g0 = wv * 64;                     // output block base in [0,512)
  const int ksb = (g0 < 256) ? 0 : 4;         // W1a vs W1b packed ks base
  const int ncol = (g0 < 256) ? g0 : (g0 - 256);

  floatx4 acc[2][4];
  #pragma unroll
  for (int mi = 0; mi < 2; ++mi)
    #pragma unroll
    for (int ni = 0; ni < 4; ++ni) acc[mi][ni] = (floatx4){0.f, 0.f, 0.f, 0.f};

  for (int ks = 0; ks < 4; ++ks) {
    bf16x8 a0 = *(const bf16x8*)&A16[ln15 * 136 + ks * 32 + quad * 8];
    bf16x8 a1 = *(const bf16x8*)&A16[(16 + ln15) * 136 + ks * 32 + quad * 8];
    #pragma unroll
    for (int ni = 0; ni < 4; ++ni) {
      bf16x8 b = *(const bf16x8*)&W1p[((size_t)((ksb + ks) * 256 + ncol + ni * 16 + ln15) << 5) + quad * 8];
      acc[0][ni] = MFMA16x32(a0, b, acc[0][ni]);
      acc[1][ni] = MFMA16x32(a1, b, acc[1][ni]);
    }
  }

  float bbv[4];
  #pragma unroll
  for (int ni = 0; ni < 4; ++ni)
    bbv[ni] = (g0 < 256) ? b1p[ncol + ni * 16 + ln15] : 0.0f;

  #pragma unroll
  for (int mi = 0; mi < 2; ++mi)
    #pragma unroll
    for (int r = 0; r < 4; ++r) {
      int row = mi * 16 + quad * 4 + r;
      int g = base + row;
      if (g < NN) {
        float v0 = acc[mi][0][r] + bbv[0];
        float v1 = acc[mi][1][r] + bbv[1];
        float v2 = acc[mi][2][r] + bbv[2];
        float v3 = acc[mi][3][r] + bbv[3];
        uint2 pv;
        pv.x = pk2(v0, v1);
        pv.y = pk2(v2, v3);
        *(uint2*)&Hpre[(size_t)g * 512 + g0 + ln15 * 4] = pv;
      }
    }
}

// ---------------- edge MLP (MFMA): 32 edges/block, 4 waves ----------------
// GEMM1 reduced to K=128 (e @ W1c, packed ks 8-11); h-dependent terms + b1 come
// from bf16 permuted-Hpre gather (two 8B loads per accumulator row).
__global__ __launch_bounds__(256) void k_edge_mlp_mfma(
    const ushort_t* __restrict__ Hpre, float* __restrict__ e, ushort_t* __restrict__ e_bf,
    const int* __restrict__ eidx,
    const ushort_t* __restrict__ W1pk, const ushort_t* __restrict__ W2pk,
    const float* __restrict__ g1, const float* __restrict__ bt1,
    const float* __restrict__ b2, const float* __restrict__ g2, const float* __restrict__ bt2,
    int layer)
{
  __shared__ __align__(16) ushort_t A16[32 * 136];   // e tile only
  __shared__ __align__(16) ushort_t Z16[32 * 264];
  __shared__ float red_s[32 * 4], red_q[32 * 4];
  __shared__ int s_row[32], s_col[32];

  const int tid = threadIdx.x;
  const int base = blockIdx.x * 32;
  const ushort_t* W1p = W1pk + (size_t)layer * (12 * 256 * 32);
  const ushort_t* W2p = W2pk + (size_t)layer * (8 * 128 * 32);
  const float* g1p = g1 + layer * 256;
  const float* bt1p = bt1 + layer * 256;
  const float* b2p = b2 + layer * 128;
  const float* g2p = g2 + layer * 128;
  const float* bt2p = bt2 + layer * 128;

  if (tid < 32) s_row[tid] = eidx[base + tid];
  else if (tid < 64) s_col[tid - 32] = eidx[EE + base + (tid - 32)];
  __syncthreads();

  // stage e (bf16 mirror): 32 edges x 16 chunks of 8 -> 2 chunks/thread
  #pragma unroll
  for (int i = 0; i < 2; ++i) {
    int idx = tid + i * 256;
    int ei = idx >> 4, c = idx & 15;
    *(uint4*)&A16[ei * 136 + c * 8] =
        *(const uint4*)(e_bf + (size_t)(base + ei) * 128 + c * 8);
  }
  __syncthreads();

  const int lane = tid & 63;
  const int wv = tid >> 6;
  const int ln15 = lane & 15;
  const int quad = lane >> 4;

  // ---- GEMM1 (K=128): [32x128] @ [128x256] using packed ks 8-11 ----
  floatx4 acc[2][4];
  #pragma unroll
  for (int mi = 0; mi < 2; ++mi)
    #pragma unroll
    for (int ni = 0; ni < 4; ++ni) acc[mi][ni] = (floatx4){0.f, 0.f, 0.f, 0.f};

  const int nb1 = wv * 64;
  for (int ks = 0; ks < 4; ++ks) {
    bf16x8 a0 = *(const bf16x8*)&A16[ln15 * 136 + ks * 32 + quad * 8];
    bf16x8 a1 = *(const bf16x8*)&A16[(16 + ln15) * 136 + ks * 32 + quad * 8];
    #pragma unroll
    for (int ni = 0; ni < 4; ++ni) {
      bf16x8 b = *(const bf16x8*)&W1p[((size_t)((8 + ks) * 256 + nb1 + ni * 16 + ln15) << 5) + quad * 8];
      acc[0][ni] = MFMA16x32(a0, b, acc[0][ni]);
      acc[1][ni] = MFMA16x32(a1, b, acc[1][ni]);
    }
  }

  // add Hpre gather (bf16, permuted): per row two contiguous 8B loads
  {
    const int po = nb1 + ln15 * 4;
    #pragma unroll
    for (int mi = 0; mi < 2; ++mi)
      #pragma unroll
      for (int r = 0; r < 4; ++r) {
        int row = mi * 16 + quad * 4 + r;
        uint2 vr = *(const uint2*)(Hpre + (size_t)s_row[row] * 512 + po);
        uint2 vc = *(const uint2*)(Hpre + (size_t)s_col[row] * 512 + 256 + po);
        acc[mi][0][r] += __uint_as_float(vr.x << 16) + __uint_as_float(vc.x << 16);
        acc[mi][1][r] += __uint_as_float(vr.x & 0xFFFF0000u) + __uint_as_float(vc.x & 0xFFFF0000u);
        acc[mi][2][r] += __uint_as_float(vr.y << 16) + __uint_as_float(vc.y << 16);
        acc[mi][3][r] += __uint_as_float(vr.y & 0xFFFF0000u) + __uint_as_float(vc.y & 0xFFFF0000u);
      }
  }

  // LN1 partials
  #pragma unroll
  for (int mi = 0; mi < 2; ++mi)
    #pragma unroll
    for (int r = 0; r < 4; ++r) {
      float v = 0.f, u = 0.f;
      #pragma unroll
      for (int ni = 0; ni < 4; ++ni) { float x = acc[mi][ni][r]; v += x; u += x * x; }
      v = row16_sum(v); u = row16_sum(u);
      if (ln15 == 0) {
        int row = mi * 16 + quad * 4 + r;
        red_s[row * 4 + wv] = v; red_q[row * 4 + wv] = u;
      }
    }
  __syncthreads();

  float mrow[2][4], rrow[2][4];
  #pragma unroll
  for (int mi = 0; mi < 2; ++mi)
    #pragma unroll
    for (int r = 0; r < 4; ++r) {
      int row = mi * 16 + quad * 4 + r;
      float S = red_s[row * 4] + red_s[row * 4 + 1] + red_s[row * 4 + 2] + red_s[row * 4 + 3];
      float Q = red_q[row * 4] + red_q[row * 4 + 1] + red_q[row * 4 + 2] + red_q[row * 4 + 3];
      float m = S * (1.f / 256.f);
      float var = Q * (1.f / 256.f) - m * m;
      mrow[mi][r] = m; rrow[mi][r] = rsqrtf(var + 1e-5f);
    }
  #pragma unroll
  for (int ni = 0; ni < 4; ++ni) {
    int col = nb1 + ni * 16 + ln15;
    float gg = g1p[col], bb = bt1p[col];
    #pragma unroll
    for (int mi = 0; mi < 2; ++mi)
      #pragma unroll
      for (int r = 0; r < 4; ++r) {
        int row = mi * 16 + quad * 4 + r;
        float z = (acc[mi][ni][r] - mrow[mi][r]) * rrow[mi][r] * gg + bb;
        Z16[row * 264 + col] = f2b(gelu_fast(z));
      }
  }
  __syncthreads();

  // ---- GEMM2: [32x256] @ [256x128], ks ping-pong B prefetch ----
  floatx4 c2[2][2];
  #pragma unroll
  for (int mi = 0; mi < 2; ++mi)
    #pragma unroll
    for (int ni = 0; ni < 2; ++ni) c2[mi][ni] = (floatx4){0.f, 0.f, 0.f, 0.f};

  const int nb2 = wv * 32;
  {
    const ushort_t* Wf = W2p + ((size_t)(nb2 + ln15) << 5) + quad * 8;
    bf16x8 bA[2], bB[2];
    #pragma unroll
    for (int ni = 0; ni < 2; ++ni) bA[ni] = *(const bf16x8*)(Wf + (size_t)ni * (16 << 5));
    #pragma unroll
    for (int ks = 0; ks < 8; ks += 2) {
      #pragma unroll
      for (int ni = 0; ni < 2; ++ni)
        bB[ni] = *(const bf16x8*)(Wf + (size_t)(ks + 1) * (128 << 5) + (size_t)ni * (16 << 5));
      {
        bf16x8 a0 = *(const bf16x8*)&Z16[ln15 * 264 + ks * 32 + quad * 8];
        bf16x8 a1 = *(const bf16x8*)&Z16[(16 + ln15) * 264 + ks * 32 + quad * 8];
        #pragma unroll
        for (int ni = 0; ni < 2; ++ni) {
          c2[0][ni] = MFMA16x32(a0, bA[ni], c2[0][ni]);
          c2[1][ni] = MFMA16x32(a1, bA[ni], c2[1][ni]);
        }
      }
      if (ks + 2 < 8) {
        #pragma unroll
        for (int ni = 0; ni < 2; ++ni)
          bA[ni] = *(const bf16x8*)(Wf + (size_t)(ks + 2) * (128 << 5) + (size_t)ni * (16 << 5));
      }
      {
        bf16x8 a0 = *(const bf16x8*)&Z16[ln15 * 264 + (ks + 1) * 32 + quad * 8];
        bf16x8 a1 = *(const bf16x8*)&Z16[(16 + ln15) * 264 + (ks + 1) * 32 + quad * 8];
        #pragma unroll
        for (int ni = 0; ni < 2; ++ni) {
          c2[0][ni] = MFMA16x32(a0, bB[ni], c2[0][ni]);
          c2[1][ni] = MFMA16x32(a1, bB[ni], c2[1][ni]);
        }
      }
    }
  }

  #pragma unroll
  for (int ni = 0; ni < 2; ++ni) {
    float bb = b2p[nb2 + ni * 16 + ln15];
    #pragma unroll
    for (int mi = 0; mi < 2; ++mi)
      #pragma unroll
      for (int r = 0; r < 4; ++r) c2[mi][ni][r] += bb;
  }
  #pragma unroll
  for (int mi = 0; mi < 2; ++mi)
    #pragma unroll
    for (int r = 0; r < 4; ++r) {
      float v = 0.f, u = 0.f;
      #pragma unroll
      for (int ni = 0; ni < 2; ++ni) { float x = c2[mi][ni][r]; v += x; u += x * x; }
      v = row16_sum(v); u = row16_sum(u);
      if (ln15 == 0) {
        int row = mi * 16 + quad * 4 + r;
        red_s[row * 4 + wv] = v; red_q[row * 4 + wv] = u;
      }
    }
  __syncthreads();

  #pragma unroll
  for (int mi = 0; mi < 2; ++mi)
    #pragma unroll
    for (int r = 0; r < 4; ++r) {
      int row = mi * 16 + quad * 4 + r;
      float S = red_s[row * 4] + red_s[row * 4 + 1] + red_s[row * 4 + 2] + red_s[row * 4 + 3];
      float Q = red_q[row * 4] + red_q[row * 4 + 1] + red_q[row * 4 + 2] + red_q[row * 4 + 3];
      float m = S * (1.f / 128.f);
      float var = Q * (1.f / 128.f) - m * m;
      mrow[mi][r] = m; rrow[mi][r] = rsqrtf(var + 1e-5f);
    }
  #pragma unroll
  for (int ni = 0; ni < 2; ++ni) {
    int col = nb2 + ni * 16 + ln15;
    float gg = g2p[col], bb = bt2p[col];
    #pragma unroll
    for (int mi = 0; mi < 2; ++mi)
      #pragma unroll
      for (int r = 0; r < 4; ++r) {
        int row = mi * 16 + quad * 4 + r;
        float z = (c2[mi][ni][r] - mrow[mi][r]) * rrow[mi][r] * gg + bb;
        size_t gi = (size_t)(base + row) * 128 + col;
        float nv = e[gi] + z;
        e[gi] = nv;
        e_bf[gi] = f2b(nv);
      }
  }
}

// ---------------- node MLP (MFMA, fused scatter-mean): 32 nodes/block ----------------
__global__ __launch_bounds__(256) void k_node_mlp_mfma(
    float* __restrict__ h, ushort_t* __restrict__ h_bf, const ushort_t* __restrict__ e_bf,
    const int* __restrict__ rowptr, const int* __restrict__ edge_of,
    const ushort_t* __restrict__ W1pk, const ushort_t* __restrict__ W2pk,
    const float* __restrict__ b1, const float* __restrict__ g1, const float* __restrict__ bt1,
    const float* __restrict__ b2, const float* __restrict__ g2, const float* __restrict__ bt2,
    int layer)
{
  __shared__ __align__(16) ushort_t A16[32 * 264];
  __shared__ float red_s[32 * 4], red_q[32 * 4];
  ushort_t* Z16 = A16;

  const int tid = threadIdx.x;
  const int base = blockIdx.x * 32;
  const ushort_t* W1p = W1pk + (size_t)layer * (8 * 256 * 32);
  const ushort_t* W2p = W2pk + (size_t)layer * (8 * 128 * 32);
  const float* b1p = b1 + layer * 256;
  const float* g1p = g1 + layer * 256;
  const float* bt1p = bt1 + layer * 256;
  const float* b2p = b2 + layer * 128;
  const float* g2p = g2 + layer * 128;
  const float* bt2p = bt2 + layer * 128;

  // staging: 8 threads/node; seg owns 16 cols of h and 16 cols of agg
  {
    const int node = tid >> 3, seg = tid & 7;
    const int g = base + node;
    if (g < NN) {
      *(uint4*)&A16[node * 264 + seg * 16] =
          *(const uint4*)(h_bf + (size_t)g * 128 + seg * 16);
      *(uint4*)&A16[node * 264 + seg * 16 + 8] =
          *(const uint4*)(h_bf + (size_t)g * 128 + seg * 16 + 8);
      const int s = rowptr[g], en = rowptr[g + 1];
      float a[16];
      #pragma unroll
      for (int q = 0; q < 16; ++q) a[q] = 0.f;
      for (int it = s; it < en; ++it) {
        const ushort_t* src = e_bf + (size_t)edge_of[it] * 128 + seg * 16;
        uint4 v0 = *(const uint4*)src;
        uint4 v1 = *(const uint4*)(src + 8);
        a[0] += __uint_as_float(v0.x << 16); a[1] += __uint_as_float(v0.x & 0xFFFF0000u);
        a[2] += __uint_as_float(v0.y << 16); a[3] += __uint_as_float(v0.y & 0xFFFF0000u);
        a[4] += __uint_as_float(v0.z << 16); a[5] += __uint_as_float(v0.z & 0xFFFF0000u);
        a[6] += __uint_as_float(v0.w << 16); a[7] += __uint_as_float(v0.w & 0xFFFF0000u);
        a[8]  += __uint_as_float(v1.x << 16); a[9]  += __uint_as_float(v1.x & 0xFFFF0000u);
        a[10] += __uint_as_float(v1.y << 16); a[11] += __uint_as_float(v1.y & 0xFFFF0000u);
        a[12] += __uint_as_float(v1.z << 16); a[13] += __uint_as_float(v1.z & 0xFFFF0000u);
        a[14] += __uint_as_float(v1.w << 16); a[15] += __uint_as_float(v1.w & 0xFFFF0000u);
      }
      int c = en - s;
      float inv = 1.0f / (float)(c > 0 ? c : 1);
      uint4 p0, p1;
      p0.x = pk2(a[0] * inv, a[1] * inv);  p0.y = pk2(a[2] * inv, a[3] * inv);
      p0.z = pk2(a[4] * inv, a[5] * inv);  p0.w = pk2(a[6] * inv, a[7] * inv);
      p1.x = pk2(a[8] * inv, a[9] * inv);  p1.y = pk2(a[10] * inv, a[11] * inv);
      p1.z = pk2(a[12] * inv, a[13] * inv); p1.w = pk2(a[14] * inv, a[15] * inv);
      *(uint4*)&A16[node * 264 + 128 + seg * 16] = p0;
      *(uint4*)&A16[node * 264 + 128 + seg * 16 + 8] = p1;
    } else {
      uint4 zz = {0u, 0u, 0u, 0u};
      *(uint4*)&A16[node * 264 + seg * 16] = zz;
      *(uint4*)&A16[node * 264 + seg * 16 + 8] = zz;
      *(uint4*)&A16[node * 264 + 128 + seg * 16] = zz;
      *(uint4*)&A16[node * 264 + 128 + seg * 16 + 8] = zz;
    }
  }
  __syncthreads();

  const int lane = tid & 63;
  const int wv = tid >> 6;
  const int ln15 = lane & 15;
  const int quad = lane >> 4;

  // ---- GEMM1: [32x256] @ [256x256]; wave: 2 m-tiles x 4 n-tiles ----
  floatx4 acc[2][4];
  #pragma unroll
  for (int mi = 0; mi < 2; ++mi)
    #pragma unroll
    for (int ni = 0; ni < 4; ++ni) acc[mi][ni] = (floatx4){0.f, 0.f, 0.f, 0.f};

  const int nb1 = wv * 64;
  for (int ks = 0; ks < 8; ++ks) {
    bf16x8 a0 = *(const bf16x8*)&A16[ln15 * 264 + ks * 32 + quad * 8];
    bf16x8 a1 = *(const bf16x8*)&A16[(16 + ln15) * 264 + ks * 32 + quad * 8];
    #pragma unroll
    for (int ni = 0; ni < 4; ++ni) {
      bf16x8 b = *(const bf16x8*)&W1p[((size_t)(ks * 256 + nb1 + ni * 16 + ln15) << 5) + quad * 8];
      acc[0][ni] = MFMA16x32(a0, b, acc[0][ni]);
      acc[1][ni] = MFMA16x32(a1, b, acc[1][ni]);
    }
  }

  #pragma unroll
  for (int ni = 0; ni < 4; ++ni) {
    float bb = b1p[nb1 + ni * 16 + ln15];
    #pragma unroll
    for (int mi = 0; mi < 2; ++mi)
      #pragma unroll
      for (int r = 0; r < 4; ++r) acc[mi][ni][r] += bb;
  }
  #pragma unroll
  for (int mi = 0; mi < 2; ++mi)
    #pragma unroll
    for (int r = 0; r < 4; ++r) {
      float v = 0.f, u = 0.f;
      #pragma unroll
      for (int ni = 0; ni < 4; ++ni) { float x = acc[mi][ni][r]; v += x; u += x * x; }
      v = row16_sum(v); u = row16_sum(u);
      if (ln15 == 0) {
        int row = mi * 16 + quad * 4 + r;
        red_s[row * 4 + wv] = v; red_q[row * 4 + wv] = u;
      }
    }
  __syncthreads();

  float mrow[2][4], rrow[2][4];
  #pragma unroll
  for (int mi = 0; mi < 2; ++mi)
    #pragma unroll
    for (int r = 0; r < 4; ++r) {
      int row = mi * 16 + quad * 4 + r;
      float S = red_s[row * 4] + red_s[row * 4 + 1] + red_s[row * 4 + 2] + red_s[row * 4 + 3];
      float Q = red_q[row * 4] + red_q[row * 4 + 1] + red_q[row * 4 + 2] + red_q[row * 4 + 3];
      float m = S * (1.f / 256.f);
      float var = Q * (1.f / 256.f) - m * m;
      mrow[mi][r] = m; rrow[mi][r] = rsqrtf(var + 1e-5f);
    }
  #pragma unroll
  for (int ni = 0; ni < 4; ++ni) {
    int col = nb1 + ni * 16 + ln15;
    float gg = g1p[col], bb = bt1p[col];
    #pragma unroll
    for (int mi = 0; mi < 2; ++mi)
      #pragma unroll
      for (int r = 0; r < 4; ++r) {
        int row = mi * 16 + quad * 4 + r;
        float z = (acc[mi][ni][r] - mrow[mi][r]) * rrow[mi][r] * gg + bb;
        Z16[row * 264 + col] = f2b(gelu_fast(z));
      }
  }
  __syncthreads();

  // ---- GEMM2: [32x256] @ [256x128]; wave: 2 m-tiles x 2 n-tiles ----
  floatx4 c2[2][2];
  #pragma unroll
  for (int mi = 0; mi < 2; ++mi)
    #pragma unroll
    for (int ni = 0; ni < 2; ++ni) c2[mi][ni] = (floatx4){0.f, 0.f, 0.f, 0.f};

  const int nb2 = wv * 32;
  for (int ks = 0; ks < 8; ++ks) {
    bf16x8 a0 = *(const bf16x8*)&Z16[ln15 * 264 + ks * 32 + quad * 8];
    bf16x8 a1 = *(const bf16x8*)&Z16[(16 + ln15) * 264 + ks * 32 + quad * 8];
    #pragma unroll
    for (int ni = 0; ni < 2; ++ni) {
      bf16x8 b = *(const bf16x8*)&W2p[((size_t)(ks * 128 + nb2 + ni * 16 + ln15) << 5) + quad * 8];
      c2[0][ni] = MFMA16x32(a0, b, c2[0][ni]);
      c2[1][ni] = MFMA16x32(a1, b, c2[1][ni]);
    }
  }

  #pragma unroll
  for (int ni = 0; ni < 2; ++ni) {
    float bb = b2p[nb2 + ni * 16 + ln15];
    #pragma unroll
    for (int mi = 0; mi < 2; ++mi)
      #pragma unroll
      for (int r = 0; r < 4; ++r) c2[mi][ni][r] += bb;
  }
  #pragma unroll
  for (int mi = 0; mi < 2; ++mi)
    #pragma unroll
    for (int r = 0; r < 4; ++r) {
      float v = 0.f, u = 0.f;
      #pragma unroll
      for (int ni = 0; ni < 2; ++ni) { float x = c2[mi][ni][r]; v += x; u += x * x; }
      v = row16_sum(v); u = row16_sum(u);
      if (ln15 == 0) {
        int row = mi * 16 + quad * 4 + r;
        red_s[row * 4 + wv] = v; red_q[row * 4 + wv] = u;
      }
    }
  __syncthreads();

  #pragma unroll
  for (int mi = 0; mi < 2; ++mi)
    #pragma unroll
    for (int r = 0; r < 4; ++r) {
      int row = mi * 16 + quad * 4 + r;
      float S = red_s[row * 4] + red_s[row * 4 + 1] + red_s[row * 4 + 2] + red_s[row * 4 + 3];
      float Q = red_q[row * 4] + red_q[row * 4 + 1] + red_q[row * 4 + 2] + red_q[row * 4 + 3];
      float m = S * (1.f / 128.f);
      float var = Q * (1.f / 128.f) - m * m;
      mrow[mi][r] = m; rrow[mi][r] = rsqrtf(var + 1e-5f);
    }
  #pragma unroll
  for (int ni = 0; ni < 2; ++ni) {
    int col = nb2 + ni * 16 + ln15;
    float gg = g2p[col], bb = bt2p[col];
    #pragma unroll
    for (int mi = 0; mi < 2; ++mi)
      #pragma unroll
      for (int r = 0; r < 4; ++r) {
        int row = mi * 16 + quad * 4 + r;
        int g = base + row;
        if (g < NN) {
          float z = (c2[mi][ni][r] - mrow[mi][r]) * rrow[mi][r] * gg + bb;
          size_t gi = (size_t)g * 128 + col;
          float nv = h[gi] + z;
          h[gi] = nv;
          h_bf[gi] = f2b(nv);
        }
      }
  }
}

// ---------------- decoder ----------------
__global__ __launch_bounds__(128) void k_decoder(
    const float* __restrict__ h, const float* __restrict__ W1,
    const float* __restrict__ b1, const float* __restrict__ W2,
    const float* __restrict__ b2, float* __restrict__ out)
{
  const int n = blockIdx.x;
  const int j = threadIdx.x;
  __shared__ float hs[128];
  __shared__ float z1s[128];
  hs[j] = h[(size_t)n * 128 + j];
  __syncthreads();
  float z = b1[j];
  for (int k = 0; k < 128; ++k) z = fmaf(hs[k], W1[k * 128 + j], z);
  z1s[j] = gelu_exact(z);
  __syncthreads();
  if (j < 4) {
    float o = b2[j];
    for (int k = 0; k < 128; ++k) o = fmaf(z1s[k], W2[k * 4 + j], o);
    out[n * 4 + j] = o;
  }
}

static inline char* align_up(char* p, size_t a) {
  return (char*)(((uintptr_t)p + (a - 1)) & ~(uintptr_t)(a - 1));
}

extern "C" void kernel_launch(void* const* d_in, const int* in_sizes, int n_in,
                              void* d_out, int out_size, void* d_ws, size_t ws_size,
                              hipStream_t stream) {
  const float* x     = (const float*)d_in[0];
  const int*   eidx  = (const int*)d_in[1];
  const float* ea    = (const float*)d_in[2];
  const float* encW  = (const float*)d_in[3];
  const float* encb  = (const float*)d_in[4];
  const float* encg  = (const float*)d_in[5];
  const float* encbt = (const float*)d_in[6];
  const float* eencW = (const float*)d_in[7];
  const float* eencb = (const float*)d_in[8];
  const float* eW1   = (const float*)d_in[9];
  const float* eb1   = (const float*)d_in[10];
  const float* eg1   = (const float*)d_in[11];
  const float* ebt1  = (const float*)d_in[12];
  const float* eW2   = (const float*)d_in[13];
  const float* eb2   = (const float*)d_in[14];
  const float* eg2   = (const float*)d_in[15];
  const float* ebt2  = (const float*)d_in[16];
  const float* nW1   = (const float*)d_in[17];
  const float* nb1   = (const float*)d_in[18];
  const float* ng1   = (const float*)d_in[19];
  const float* nbt1  = (const float*)d_in[20];
  const float* nW2   = (const float*)d_in[21];
  const float* nb2   = (const float*)d_in[22];
  const float* ng2   = (const float*)d_in[23];
  const float* nbt2  = (const float*)d_in[24];
  const float* dW1   = (const float*)d_in[25];
  const float* db1   = (const float*)d_in[26];
  const float* dW2   = (const float*)d_in[27];
  const float* db2   = (const float*)d_in[28];
  float* out = (float*)d_out;

  char* p = (char*)d_ws;
  float* h   = (float*)p; p += (size_t)NN * 128 * 4;
  float* e   = (float*)p; p += (size_t)EE * 128 * 4;
  int* cnt     = (int*)p; p += (size_t)NN * 4;
  int* rowptr  = (int*)p; p += (size_t)(NN + 1) * 4;
  int* fillp   = (int*)p; p += (size_t)NN * 4;
  int* edge_of = (int*)p; p += (size_t)EE * 4;
  p = align_up(p, 256);
  ushort_t* h_bf = (ushort_t*)p; p += (size_t)NN * 128 * 2;
  p = align_up(p, 256);
  ushort_t* e_bf = (ushort_t*)p; p += (size_t)EE * 128 * 2;
  p = align_up(p, 256);
  ushort_t* Hpre = (ushort_t*)p; p += (size_t)NN * 512 * 2;
  p = align_up(p, 256);
  ushort_t* eW1pk = (ushort_t*)p; p += (size_t)L_LAYERS * 12 * 256 * 32 * 2;
  p = align_up(p, 256);
  ushort_t* eW2pk = (ushort_t*)p; p += (size_t)L_LAYERS * 8 * 128 * 32 * 2;
  p = align_up(p, 256);
  ushort_t* nW1pk = (ushort_t*)p; p += (size_t)L_LAYERS * 8 * 256 * 32 * 2;
  p = align_up(p, 256);
  ushort_t* nW2pk = (ushort_t*)p; p += (size_t)L_LAYERS * 8 * 128 * 32 * 2;

  {
    int n1 = L_LAYERS * 384 * 256;
    k_pack_w<<<(n1 + 255) / 256, 256, 0, stream>>>(eW1, eW1pk, 384, 256, n1);
    int n2 = L_LAYERS * 256 * 128;
    k_pack_w<<<(n2 + 255) / 256, 256, 0, stream>>>(eW2, eW2pk, 256, 128, n2);
    int n3 = L_LAYERS * 256 * 256;
    k_pack_w<<<(n3 + 255) / 256, 256, 0, stream>>>(nW1, nW1pk, 256, 256, n3);
    int n4 = L_LAYERS * 256 * 128;
    k_pack_w<<<(n4 + 255) / 256, 256, 0, stream>>>(nW2, nW2pk, 256, 128, n4);
  }

  k_encoder<<<NN, 128, 0, stream>>>(x, encW, encb, encg, encbt, h, h_bf);
  k_edge_enc<<<(EE * 128) / 256, 256, 0, stream>>>(ea, eencW, eencb, e, e_bf);
  k_zero_cnt<<<(NN + 255) / 256, 256, 0, stream>>>(cnt);
  k_count<<<EE / 256, 256, 0, stream>>>(eidx, cnt);
  k_scan<<<1, 256, 0, stream>>>(cnt, rowptr, fillp);
  k_fill<<<EE / 256, 256, 0, stream>>>(eidx, fillp, edge_of);

  for (int l = 0; l < L_LAYERS; ++l) {
    k_hpre<<<(NN + 31) / 32, 512, 0, stream>>>(h_bf, eW1pk, eb1, Hpre, l);
    k_edge_mlp_mfma<<<EE / 32, 256, 0, stream>>>(Hpre, e, e_bf, eidx,
        eW1pk, eW2pk, eg1, ebt1, eb2, eg2, ebt2, l);
    k_node_mlp_mfma<<<(NN + 31) / 32, 256, 0, stream>>>(h, h_bf, e_bf, rowptr, edge_of,
        nW1pk, nW2pk, nb1, ng1, nbt1, nb2, ng2, nbt2, l);
  }
  k_decoder<<<NN, 128, 0, stream>>>(h, dW1, db1, dW2, db2, out);
}

// Round 12
// 1457.702 us; speedup vs baseline: 1.2794x; 1.1438x over previous
//
#include <hip/hip_runtime.h>

#define L_LAYERS 10
#define NN 10000
#define EE 160000

typedef unsigned short ushort_t;
typedef unsigned int uint_t;
typedef __attribute__((ext_vector_type(8))) short bf16x8;
typedef __attribute__((ext_vector_type(4))) float floatx4;

__device__ __forceinline__ ushort_t f2b(float f) {
  uint_t u = __float_as_uint(f);
  u += 0x7FFFu + ((u >> 16) & 1u);
  return (ushort_t)(u >> 16);
}
__device__ __forceinline__ float b2f(ushort_t v) {
  return __uint_as_float(((uint_t)v) << 16);
}
__device__ __forceinline__ uint_t pk2(float lo, float hi) {
  uint_t ul = __float_as_uint(lo), uh = __float_as_uint(hi);
  ul += 0x7FFFu + ((ul >> 16) & 1u);
  uh += 0x7FFFu + ((uh >> 16) & 1u);
  return (ul >> 16) | (uh & 0xFFFF0000u);
}
__device__ __forceinline__ float gelu_exact(float x) {
  return 0.5f * x * (1.0f + erff(x * 0.7071067811865475f));
}
// tanh-form GELU: x * sigmoid(1.5957691*(x + 0.044715 x^3))
__device__ __forceinline__ float gelu_fast(float x) {
  float x2 = x * x;
  float inner = fmaf(0.044715f * x2, x, x);
  float E = __expf(-1.5957691216f * inner);
  float R = __builtin_amdgcn_rcpf(1.0f + E);
  return x * R;
}
template <int CTRL>
__device__ __forceinline__ float dpp_addf(float x) {
  int y = __builtin_amdgcn_update_dpp(0, __float_as_int(x), CTRL, 0xF, 0xF, true);
  return x + __int_as_float(y);
}
__device__ __forceinline__ float row16_sum(float x) {
  x = dpp_addf<0xB1>(x);
  x = dpp_addf<0x4E>(x);
  x = dpp_addf<0x141>(x);
  x = dpp_addf<0x140>(x);
  return x;
}
#define MFMA16x32(a, b, c) __builtin_amdgcn_mfma_f32_16x16x32_bf16((a), (b), (c), 0, 0, 0)

// ---------------- weight pack: W[L][K][N] fp32 -> P[L][K/32][N][32] bf16 ----------------
__global__ __launch_bounds__(256) void k_pack_w(
    const float* __restrict__ W, ushort_t* __restrict__ P, int K, int N, int LKN)
{
  int idx = blockIdx.x * 256 + threadIdx.x;
  if (idx >= LKN) return;
  int n = idx % N;
  int t = idx / N;
  int k = t % K;
  int l = t / K;
  int ks = k >> 5, kk = k & 31;
  int Ks = K >> 5;
  P[(((size_t)((l * Ks + ks) * N + n)) << 5) + kk] = f2b(W[idx]);
}

// ---------------- encoder ----------------
__global__ __launch_bounds__(128) void k_encoder(
    const float* __restrict__ x, const float* __restrict__ W,
    const float* __restrict__ b, const float* __restrict__ g,
    const float* __restrict__ bt, float* __restrict__ h, ushort_t* __restrict__ h_bf)
{
  const int n = blockIdx.x;
  const int j = threadIdx.x;
  __shared__ float xs[7];
  __shared__ float red[4];
  if (j < 7) xs[j] = x[n * 7 + j];
  __syncthreads();
  float z = b[j];
  #pragma unroll
  for (int k = 0; k < 7; ++k) z = fmaf(xs[k], W[k * 128 + j], z);
  float sm = z, sq = z * z;
  #pragma unroll
  for (int off = 32; off > 0; off >>= 1) {
    sm += __shfl_down(sm, off);
    sq += __shfl_down(sq, off);
  }
  const int wv = j >> 6, ln = j & 63;
  if (ln == 0) { red[wv] = sm; red[2 + wv] = sq; }
  __syncthreads();
  float m = (red[0] + red[1]) * (1.0f / 128.0f);
  float var = (red[2] + red[3]) * (1.0f / 128.0f) - m * m;
  float zz = (z - m) * rsqrtf(var + 1e-5f) * g[j] + bt[j];
  float o = gelu_exact(zz);
  h[(size_t)n * 128 + j] = o;
  h_bf[(size_t)n * 128 + j] = f2b(o);
}

// ---------------- edge encoder (bf16-only e) ----------------
__global__ __launch_bounds__(256) void k_edge_enc(
    const float* __restrict__ ea, const float* __restrict__ W,
    const float* __restrict__ b, ushort_t* __restrict__ e_bf)
{
  const int i = blockIdx.x * 256 + threadIdx.x;
  const int eid = i >> 7, j = i & 127;
  float z = b[j];
  #pragma unroll
  for (int k = 0; k < 8; ++k) z = fmaf(ea[eid * 8 + k], W[k * 128 + j], z);
  e_bf[i] = f2b(z);
}

// ---------------- CSR build ----------------
__global__ void k_zero_cnt(int* __restrict__ cnt) {
  int i = blockIdx.x * 256 + threadIdx.x;
  if (i < NN) cnt[i] = 0;
}
__global__ void k_count(const int* __restrict__ eidx, int* __restrict__ cnt) {
  int i = blockIdx.x * 256 + threadIdx.x;
  atomicAdd(&cnt[eidx[EE + i]], 1);
}
__global__ __launch_bounds__(256) void k_scan(
    const int* __restrict__ cnt, int* __restrict__ rowptr, int* __restrict__ fillp)
{
  __shared__ int tot[256];
  __shared__ int off[257];
  const int t = threadIdx.x;
  const int C = 40;
  int s = 0;
  int lo = t * C, hi = lo + C; if (hi > NN) hi = NN;
  for (int i = lo; i < hi; ++i) s += cnt[i];
  tot[t] = s;
  __syncthreads();
  if (t == 0) {
    int r = 0;
    for (int i = 0; i < 256; ++i) { off[i] = r; r += tot[i]; }
    off[256] = r;
  }
  __syncthreads();
  int r = off[t];
  for (int i = lo; i < hi; ++i) {
    rowptr[i] = r; fillp[i] = r;
    r += cnt[i];
  }
  if (t == 0) rowptr[NN] = off[256];
}
__global__ void k_fill(const int* __restrict__ eidx, int* __restrict__ fillp,
                       int* __restrict__ edge_of) {
  int i = blockIdx.x * 256 + threadIdx.x;
  int c = eidx[EE + i];
  int pos = atomicAdd(&fillp[c], 1);
  edge_of[pos] = i;
}

// ---------------- Hpre: per-node precompute of the h-dependent GEMM1 terms ----------------
// Stored bf16, C-fragment-permuted: Hpre[n][block*64 + ln15*4 + ni] holds
//   block<4 : (h[n] @ W1a + b1) at col block*64 + ni*16 + ln15      (packed ks 0-3)
//   block>=4: (h[n] @ W1b)      at col (block-4)*64 + ni*16 + ln15  (packed ks 4-7)
__global__ __launch_bounds__(512) void k_hpre(
    const ushort_t* __restrict__ h_bf, const ushort_t* __restrict__ W1pk,
    const float* __restrict__ b1, ushort_t* __restrict__ Hpre, int layer)
{
  __shared__ __align__(16) ushort_t A16[32 * 136];
  const int tid = threadIdx.x;
  const int base = blockIdx.x * 32;
  const ushort_t* W1p = W1pk + (size_t)layer * (12 * 256 * 32);
  const float* b1p = b1 + layer * 256;

  {
    const int ei = tid >> 4, c = tid & 15;
    const int g = base + ei;
    uint4 v = {0u, 0u, 0u, 0u};
    if (g < NN) v = *(const uint4*)(h_bf + (size_t)g * 128 + c * 8);
    *(uint4*)&A16[ei * 136 + c * 8] = v;
  }
  __syncthreads();

  const int lane = tid & 63;
  const int wv = tid >> 6;        // 0..7
  const int ln15 = lane & 15;
  const int quad = lane >> 4;

  const int g0 = wv * 64;
  const int ksb = (g0 < 256) ? 0 : 4;
  const int ncol = (g0 < 256) ? g0 : (g0 - 256);

  floatx4 acc[2][4];
  #pragma unroll
  for (int mi = 0; mi < 2; ++mi)
    #pragma unroll
    for (int ni = 0; ni < 4; ++ni) acc[mi][ni] = (floatx4){0.f, 0.f, 0.f, 0.f};

  for (int ks = 0; ks < 4; ++ks) {
    bf16x8 a0 = *(const bf16x8*)&A16[ln15 * 136 + ks * 32 + quad * 8];
    bf16x8 a1 = *(const bf16x8*)&A16[(16 + ln15) * 136 + ks * 32 + quad * 8];
    #pragma unroll
    for (int ni = 0; ni < 4; ++ni) {
      bf16x8 b = *(const bf16x8*)&W1p[((size_t)((ksb + ks) * 256 + ncol + ni * 16 + ln15) << 5) + quad * 8];
      acc[0][ni] = MFMA16x32(a0, b, acc[0][ni]);
      acc[1][ni] = MFMA16x32(a1, b, acc[1][ni]);
    }
  }

  float bbv[4];
  #pragma unroll
  for (int ni = 0; ni < 4; ++ni)
    bbv[ni] = (g0 < 256) ? b1p[ncol + ni * 16 + ln15] : 0.0f;

  #pragma unroll
  for (int mi = 0; mi < 2; ++mi)
    #pragma unroll
    for (int r = 0; r < 4; ++r) {
      int row = mi * 16 + quad * 4 + r;
      int g = base + row;
      if (g < NN) {
        float v0 = acc[mi][0][r] + bbv[0];
        float v1 = acc[mi][1][r] + bbv[1];
        float v2 = acc[mi][2][r] + bbv[2];
        float v3 = acc[mi][3][r] + bbv[3];
        uint2 pv;
        pv.x = pk2(v0, v1);
        pv.y = pk2(v2, v3);
        *(uint2*)&Hpre[(size_t)g * 512 + g0 + ln15 * 4] = pv;
      }
    }
}

// ---------------- edge MLP (MFMA): 32 edges/block, 4 waves; e stored bf16-only ----------------
__global__ __launch_bounds__(256) void k_edge_mlp_mfma(
    const ushort_t* __restrict__ Hpre, ushort_t* __restrict__ e_bf,
    const int* __restrict__ eidx,
    const ushort_t* __restrict__ W1pk, const ushort_t* __restrict__ W2pk,
    const float* __restrict__ g1, const float* __restrict__ bt1,
    const float* __restrict__ b2, const float* __restrict__ g2, const float* __restrict__ bt2,
    int layer)
{
  __shared__ __align__(16) ushort_t A16[32 * 136];   // e tile only
  __shared__ __align__(16) ushort_t Z16[32 * 264];
  __shared__ float red_s[32 * 4], red_q[32 * 4];
  __shared__ int s_row[32], s_col[32];

  const int tid = threadIdx.x;
  const int base = blockIdx.x * 32;
  const ushort_t* W1p = W1pk + (size_t)layer * (12 * 256 * 32);
  const ushort_t* W2p = W2pk + (size_t)layer * (8 * 128 * 32);
  const float* g1p = g1 + layer * 256;
  const float* bt1p = bt1 + layer * 256;
  const float* b2p = b2 + layer * 128;
  const float* g2p = g2 + layer * 128;
  const float* bt2p = bt2 + layer * 128;

  if (tid < 32) s_row[tid] = eidx[base + tid];
  else if (tid < 64) s_col[tid - 32] = eidx[EE + base + (tid - 32)];
  __syncthreads();

  // stage e (bf16): 32 edges x 16 chunks of 8 -> 2 chunks/thread
  #pragma unroll
  for (int i = 0; i < 2; ++i) {
    int idx = tid + i * 256;
    int ei = idx >> 4, c = idx & 15;
    *(uint4*)&A16[ei * 136 + c * 8] =
        *(const uint4*)(e_bf + (size_t)(base + ei) * 128 + c * 8);
  }
  __syncthreads();

  const int lane = tid & 63;
  const int wv = tid >> 6;
  const int ln15 = lane & 15;
  const int quad = lane >> 4;

  // ---- GEMM1 (K=128): [32x128] @ [128x256] using packed ks 8-11 ----
  floatx4 acc[2][4];
  #pragma unroll
  for (int mi = 0; mi < 2; ++mi)
    #pragma unroll
    for (int ni = 0; ni < 4; ++ni) acc[mi][ni] = (floatx4){0.f, 0.f, 0.f, 0.f};

  const int nb1 = wv * 64;
  for (int ks = 0; ks < 4; ++ks) {
    bf16x8 a0 = *(const bf16x8*)&A16[ln15 * 136 + ks * 32 + quad * 8];
    bf16x8 a1 = *(const bf16x8*)&A16[(16 + ln15) * 136 + ks * 32 + quad * 8];
    #pragma unroll
    for (int ni = 0; ni < 4; ++ni) {
      bf16x8 b = *(const bf16x8*)&W1p[((size_t)((8 + ks) * 256 + nb1 + ni * 16 + ln15) << 5) + quad * 8];
      acc[0][ni] = MFMA16x32(a0, b, acc[0][ni]);
      acc[1][ni] = MFMA16x32(a1, b, acc[1][ni]);
    }
  }

  // add Hpre gather (bf16, permuted): per row two contiguous 8B loads
  {
    const int po = nb1 + ln15 * 4;
    #pragma unroll
    for (int mi = 0; mi < 2; ++mi)
      #pragma unroll
      for (int r = 0; r < 4; ++r) {
        int row = mi * 16 + quad * 4 + r;
        uint2 vr = *(const uint2*)(Hpre + (size_t)s_row[row] * 512 + po);
        uint2 vc = *(const uint2*)(Hpre + (size_t)s_col[row] * 512 + 256 + po);
        acc[mi][0][r] += __uint_as_float(vr.x << 16) + __uint_as_float(vc.x << 16);
        acc[mi][1][r] += __uint_as_float(vr.x & 0xFFFF0000u) + __uint_as_float(vc.x & 0xFFFF0000u);
        acc[mi][2][r] += __uint_as_float(vr.y << 16) + __uint_as_float(vc.y << 16);
        acc[mi][3][r] += __uint_as_float(vr.y & 0xFFFF0000u) + __uint_as_float(vc.y & 0xFFFF0000u);
      }
  }

  // LN1 partials
  #pragma unroll
  for (int mi = 0; mi < 2; ++mi)
    #pragma unroll
    for (int r = 0; r < 4; ++r) {
      float v = 0.f, u = 0.f;
      #pragma unroll
      for (int ni = 0; ni < 4; ++ni) { float x = acc[mi][ni][r]; v += x; u += x * x; }
      v = row16_sum(v); u = row16_sum(u);
      if (ln15 == 0) {
        int row = mi * 16 + quad * 4 + r;
        red_s[row * 4 + wv] = v; red_q[row * 4 + wv] = u;
      }
    }
  __syncthreads();

  float mrow[2][4], rrow[2][4];
  #pragma unroll
  for (int mi = 0; mi < 2; ++mi)
    #pragma unroll
    for (int r = 0; r < 4; ++r) {
      int row = mi * 16 + quad * 4 + r;
      float S = red_s[row * 4] + red_s[row * 4 + 1] + red_s[row * 4 + 2] + red_s[row * 4 + 3];
      float Q = red_q[row * 4] + red_q[row * 4 + 1] + red_q[row * 4 + 2] + red_q[row * 4 + 3];
      float m = S * (1.f / 256.f);
      float var = Q * (1.f / 256.f) - m * m;
      mrow[mi][r] = m; rrow[mi][r] = rsqrtf(var + 1e-5f);
    }
  #pragma unroll
  for (int ni = 0; ni < 4; ++ni) {
    int col = nb1 + ni * 16 + ln15;
    float gg = g1p[col], bb = bt1p[col];
    #pragma unroll
    for (int mi = 0; mi < 2; ++mi)
      #pragma unroll
      for (int r = 0; r < 4; ++r) {
        int row = mi * 16 + quad * 4 + r;
        float z = (acc[mi][ni][r] - mrow[mi][r]) * rrow[mi][r] * gg + bb;
        Z16[row * 264 + col] = f2b(gelu_fast(z));
      }
  }
  __syncthreads();

  // ---- GEMM2: [32x256] @ [256x128], ks ping-pong B prefetch ----
  floatx4 c2[2][2];
  #pragma unroll
  for (int mi = 0; mi < 2; ++mi)
    #pragma unroll
    for (int ni = 0; ni < 2; ++ni) c2[mi][ni] = (floatx4){0.f, 0.f, 0.f, 0.f};

  const int nb2 = wv * 32;
  {
    const ushort_t* Wf = W2p + ((size_t)(nb2 + ln15) << 5) + quad * 8;
    bf16x8 bA[2], bB[2];
    #pragma unroll
    for (int ni = 0; ni < 2; ++ni) bA[ni] = *(const bf16x8*)(Wf + (size_t)ni * (16 << 5));
    #pragma unroll
    for (int ks = 0; ks < 8; ks += 2) {
      #pragma unroll
      for (int ni = 0; ni < 2; ++ni)
        bB[ni] = *(const bf16x8*)(Wf + (size_t)(ks + 1) * (128 << 5) + (size_t)ni * (16 << 5));
      {
        bf16x8 a0 = *(const bf16x8*)&Z16[ln15 * 264 + ks * 32 + quad * 8];
        bf16x8 a1 = *(const bf16x8*)&Z16[(16 + ln15) * 264 + ks * 32 + quad * 8];
        #pragma unroll
        for (int ni = 0; ni < 2; ++ni) {
          c2[0][ni] = MFMA16x32(a0, bA[ni], c2[0][ni]);
          c2[1][ni] = MFMA16x32(a1, bA[ni], c2[1][ni]);
        }
      }
      if (ks + 2 < 8) {
        #pragma unroll
        for (int ni = 0; ni < 2; ++ni)
          bA[ni] = *(const bf16x8*)(Wf + (size_t)(ks + 2) * (128 << 5) + (size_t)ni * (16 << 5));
      }
      {
        bf16x8 a0 = *(const bf16x8*)&Z16[ln15 * 264 + (ks + 1) * 32 + quad * 8];
        bf16x8 a1 = *(const bf16x8*)&Z16[(16 + ln15) * 264 + (ks + 1) * 32 + quad * 8];
        #pragma unroll
        for (int ni = 0; ni < 2; ++ni) {
          c2[0][ni] = MFMA16x32(a0, bB[ni], c2[0][ni]);
          c2[1][ni] = MFMA16x32(a1, bB[ni], c2[1][ni]);
        }
      }
    }
  }

  #pragma unroll
  for (int ni = 0; ni < 2; ++ni) {
    float bb = b2p[nb2 + ni * 16 + ln15];
    #pragma unroll
    for (int mi = 0; mi < 2; ++mi)
      #pragma unroll
      for (int r = 0; r < 4; ++r) c2[mi][ni][r] += bb;
  }
  #pragma unroll
  for (int mi = 0; mi < 2; ++mi)
    #pragma unroll
    for (int r = 0; r < 4; ++r) {
      float v = 0.f, u = 0.f;
      #pragma unroll
      for (int ni = 0; ni < 2; ++ni) { float x = c2[mi][ni][r]; v += x; u += x * x; }
      v = row16_sum(v); u = row16_sum(u);
      if (ln15 == 0) {
        int row = mi * 16 + quad * 4 + r;
        red_s[row * 4 + wv] = v; red_q[row * 4 + wv] = u;
      }
    }
  __syncthreads();

  #pragma unroll
  for (int mi = 0; mi < 2; ++mi)
    #pragma unroll
    for (int r = 0; r < 4; ++r) {
      int row = mi * 16 + quad * 4 + r;
      float S = red_s[row * 4] + red_s[row * 4 + 1] + red_s[row * 4 + 2] + red_s[row * 4 + 3];
      float Q = red_q[row * 4] + red_q[row * 4 + 1] + red_q[row * 4 + 2] + red_q[row * 4 + 3];
      float m = S * (1.f / 128.f);
      float var = Q * (1.f / 128.f) - m * m;
      mrow[mi][r] = m; rrow[mi][r] = rsqrtf(var + 1e-5f);
    }
  #pragma unroll
  for (int ni = 0; ni < 2; ++ni) {
    int col = nb2 + ni * 16 + ln15;
    float gg = g2p[col], bb = bt2p[col];
    #pragma unroll
    for (int mi = 0; mi < 2; ++mi)
      #pragma unroll
      for (int r = 0; r < 4; ++r) {
        int row = mi * 16 + quad * 4 + r;
        float z = (c2[mi][ni][r] - mrow[mi][r]) * rrow[mi][r] * gg + bb;
        size_t gi = (size_t)(base + row) * 128 + col;
        e_bf[gi] = f2b(b2f(e_bf[gi]) + z);
      }
  }
}

// ---------------- node MLP (MFMA, fused scatter-mean): 32 nodes/block ----------------
__global__ __launch_bounds__(256) void k_node_mlp_mfma(
    float* __restrict__ h, ushort_t* __restrict__ h_bf, const ushort_t* __restrict__ e_bf,
    const int* __restrict__ rowptr, const int* __restrict__ edge_of,
    const ushort_t* __restrict__ W1pk, const ushort_t* __restrict__ W2pk,
    const float* __restrict__ b1, const float* __restrict__ g1, const float* __restrict__ bt1,
    const float* __restrict__ b2, const float* __restrict__ g2, const float* __restrict__ bt2,
    int layer)
{
  __shared__ __align__(16) ushort_t A16[32 * 264];
  __shared__ float red_s[32 * 4], red_q[32 * 4];
  ushort_t* Z16 = A16;

  const int tid = threadIdx.x;
  const int base = blockIdx.x * 32;
  const ushort_t* W1p = W1pk + (size_t)layer * (8 * 256 * 32);
  const ushort_t* W2p = W2pk + (size_t)layer * (8 * 128 * 32);
  const float* b1p = b1 + layer * 256;
  const float* g1p = g1 + layer * 256;
  const float* bt1p = bt1 + layer * 256;
  const float* b2p = b2 + layer * 128;
  const float* g2p = g2 + layer * 128;
  const float* bt2p = bt2 + layer * 128;

  // staging: 8 threads/node; seg owns 16 cols of h and 16 cols of agg
  {
    const int node = tid >> 3, seg = tid & 7;
    const int g = base + node;
    if (g < NN) {
      *(uint4*)&A16[node * 264 + seg * 16] =
          *(const uint4*)(h_bf + (size_t)g * 128 + seg * 16);
      *(uint4*)&A16[node * 264 + seg * 16 + 8] =
          *(const uint4*)(h_bf + (size_t)g * 128 + seg * 16 + 8);
      const int s = rowptr[g], en = rowptr[g + 1];
      float a[16];
      #pragma unroll
      for (int q = 0; q < 16; ++q) a[q] = 0.f;
      for (int it = s; it < en; ++it) {
        const ushort_t* src = e_bf + (size_t)edge_of[it] * 128 + seg * 16;
        uint4 v0 = *(const uint4*)src;
        uint4 v1 = *(const uint4*)(src + 8);
        a[0] += __uint_as_float(v0.x << 16); a[1] += __uint_as_float(v0.x & 0xFFFF0000u);
        a[2] += __uint_as_float(v0.y << 16); a[3] += __uint_as_float(v0.y & 0xFFFF0000u);
        a[4] += __uint_as_float(v0.z << 16); a[5] += __uint_as_float(v0.z & 0xFFFF0000u);
        a[6] += __uint_as_float(v0.w << 16); a[7] += __uint_as_float(v0.w & 0xFFFF0000u);
        a[8]  += __uint_as_float(v1.x << 16); a[9]  += __uint_as_float(v1.x & 0xFFFF0000u);
        a[10] += __uint_as_float(v1.y << 16); a[11] += __uint_as_float(v1.y & 0xFFFF0000u);
        a[12] += __uint_as_float(v1.z << 16); a[13] += __uint_as_float(v1.z & 0xFFFF0000u);
        a[14] += __uint_as_float(v1.w << 16); a[15] += __uint_as_float(v1.w & 0xFFFF0000u);
      }
      int c = en - s;
      float inv = 1.0f / (float)(c > 0 ? c : 1);
      uint4 p0, p1;
      p0.x = pk2(a[0] * inv, a[1] * inv);  p0.y = pk2(a[2] * inv, a[3] * inv);
      p0.z = pk2(a[4] * inv, a[5] * inv);  p0.w = pk2(a[6] * inv, a[7] * inv);
      p1.x = pk2(a[8] * inv, a[9] * inv);  p1.y = pk2(a[10] * inv, a[11] * inv);
      p1.z = pk2(a[12] * inv, a[13] * inv); p1.w = pk2(a[14] * inv, a[15] * inv);
      *(uint4*)&A16[node * 264 + 128 + seg * 16] = p0;
      *(uint4*)&A16[node * 264 + 128 + seg * 16 + 8] = p1;
    } else {
      uint4 zz = {0u, 0u, 0u, 0u};
      *(uint4*)&A16[node * 264 + seg * 16] = zz;
      *(uint4*)&A16[node * 264 + seg * 16 + 8] = zz;
      *(uint4*)&A16[node * 264 + 128 + seg * 16] = zz;
      *(uint4*)&A16[node * 264 + 128 + seg * 16 + 8] = zz;
    }
  }
  __syncthreads();

  const int lane = tid & 63;
  const int wv = tid >> 6;
  const int ln15 = lane & 15;
  const int quad = lane >> 4;

  // ---- GEMM1: [32x256] @ [256x256]; wave: 2 m-tiles x 4 n-tiles ----
  floatx4 acc[2][4];
  #pragma unroll
  for (int mi = 0; mi < 2; ++mi)
    #pragma unroll
    for (int ni = 0; ni < 4; ++ni) acc[mi][ni] = (floatx4){0.f, 0.f, 0.f, 0.f};

  const int nb1 = wv * 64;
  for (int ks = 0; ks < 8; ++ks) {
    bf16x8 a0 = *(const bf16x8*)&A16[ln15 * 264 + ks * 32 + quad * 8];
    bf16x8 a1 = *(const bf16x8*)&A16[(16 + ln15) * 264 + ks * 32 + quad * 8];
    #pragma unroll
    for (int ni = 0; ni < 4; ++ni) {
      bf16x8 b = *(const bf16x8*)&W1p[((size_t)(ks * 256 + nb1 + ni * 16 + ln15) << 5) + quad * 8];
      acc[0][ni] = MFMA16x32(a0, b, acc[0][ni]);
      acc[1][ni] = MFMA16x32(a1, b, acc[1][ni]);
    }
  }

  #pragma unroll
  for (int ni = 0; ni < 4; ++ni) {
    float bb = b1p[nb1 + ni * 16 + ln15];
    #pragma unroll
    for (int mi = 0; mi < 2; ++mi)
      #pragma unroll
      for (int r = 0; r < 4; ++r) acc[mi][ni][r] += bb;
  }
  #pragma unroll
  for (int mi = 0; mi < 2; ++mi)
    #pragma unroll
    for (int r = 0; r < 4; ++r) {
      float v = 0.f, u = 0.f;
      #pragma unroll
      for (int ni = 0; ni < 4; ++ni) { float x = acc[mi][ni][r]; v += x; u += x * x; }
      v = row16_sum(v); u = row16_sum(u);
      if (ln15 == 0) {
        int row = mi * 16 + quad * 4 + r;
        red_s[row * 4 + wv] = v; red_q[row * 4 + wv] = u;
      }
    }
  __syncthreads();

  float mrow[2][4], rrow[2][4];
  #pragma unroll
  for (int mi = 0; mi < 2; ++mi)
    #pragma unroll
    for (int r = 0; r < 4; ++r) {
      int row = mi * 16 + quad * 4 + r;
      float S = red_s[row * 4] + red_s[row * 4 + 1] + red_s[row * 4 + 2] + red_s[row * 4 + 3];
      float Q = red_q[row * 4] + red_q[row * 4 + 1] + red_q[row * 4 + 2] + red_q[row * 4 + 3];
      float m = S * (1.f / 256.f);
      float var = Q * (1.f / 256.f) - m * m;
      mrow[mi][r] = m; rrow[mi][r] = rsqrtf(var + 1e-5f);
    }
  #pragma unroll
  for (int ni = 0; ni < 4; ++ni) {
    int col = nb1 + ni * 16 + ln15;
    float gg = g1p[col], bb = bt1p[col];
    #pragma unroll
    for (int mi = 0; mi < 2; ++mi)
      #pragma unroll
      for (int r = 0; r < 4; ++r) {
        int row = mi * 16 + quad * 4 + r;
        float z = (acc[mi][ni][r] - mrow[mi][r]) * rrow[mi][r] * gg + bb;
        Z16[row * 264 + col] = f2b(gelu_fast(z));
      }
  }
  __syncthreads();

  // ---- GEMM2: [32x256] @ [256x128]; wave: 2 m-tiles x 2 n-tiles ----
  floatx4 c2[2][2];
  #pragma unroll
  for (int mi = 0; mi < 2; ++mi)
    #pragma unroll
    for (int ni = 0; ni < 2; ++ni) c2[mi][ni] = (floatx4){0.f, 0.f, 0.f, 0.f};

  const int nb2 = wv * 32;
  for (int ks = 0; ks < 8; ++ks) {
    bf16x8 a0 = *(const bf16x8*)&Z16[ln15 * 264 + ks * 32 + quad * 8];
    bf16x8 a1 = *(const bf16x8*)&Z16[(16 + ln15) * 264 + ks * 32 + quad * 8];
    #pragma unroll
    for (int ni = 0; ni < 2; ++ni) {
      bf16x8 b = *(const bf16x8*)&W2p[((size_t)(ks * 128 + nb2 + ni * 16 + ln15) << 5) + quad * 8];
      c2[0][ni] = MFMA16x32(a0, b, c2[0][ni]);
      c2[1][ni] = MFMA16x32(a1, b, c2[1][ni]);
    }
  }

  #pragma unroll
  for (int ni = 0; ni < 2; ++ni) {
    float bb = b2p[nb2 + ni * 16 + ln15];
    #pragma unroll
    for (int mi = 0; mi < 2; ++mi)
      #pragma unroll
      for (int r = 0; r < 4; ++r) c2[mi][ni][r] += bb;
  }
  #pragma unroll
  for (int mi = 0; mi < 2; ++mi)
    #pragma unroll
    for (int r = 0; r < 4; ++r) {
      float v = 0.f, u = 0.f;
      #pragma unroll
      for (int ni = 0; ni < 2; ++ni) { float x = c2[mi][ni][r]; v += x; u += x * x; }
      v = row16_sum(v); u = row16_sum(u);
      if (ln15 == 0) {
        int row = mi * 16 + quad * 4 + r;
        red_s[row * 4 + wv] = v; red_q[row * 4 + wv] = u;
      }
    }
  __syncthreads();

  #pragma unroll
  for (int mi = 0; mi < 2; ++mi)
    #pragma unroll
    for (int r = 0; r < 4; ++r) {
      int row = mi * 16 + quad * 4 + r;
      float S = red_s[row * 4] + red_s[row * 4 + 1] + red_s[row * 4 + 2] + red_s[row * 4 + 3];
      float Q = red_q[row * 4] + red_q[row * 4 + 1] + red_q[row * 4 + 2] + red_q[row * 4 + 3];
      float m = S * (1.f / 128.f);
      float var = Q * (1.f / 128.f) - m * m;
      mrow[mi][r] = m; rrow[mi][r] = rsqrtf(var + 1e-5f);
    }
  #pragma unroll
  for (int ni = 0; ni < 2; ++ni) {
    int col = nb2 + ni * 16 + ln15;
    float gg = g2p[col], bb = bt2p[col];
    #pragma unroll
    for (int mi = 0; mi < 2; ++mi)
      #pragma unroll
      for (int r = 0; r < 4; ++r) {
        int row = mi * 16 + quad * 4 + r;
        int g = base + row;
        if (g < NN) {
          float z = (c2[mi][ni][r] - mrow[mi][r]) * rrow[mi][r] * gg + bb;
          size_t gi = (size_t)g * 128 + col;
          float nv = h[gi] + z;
          h[gi] = nv;
          h_bf[gi] = f2b(nv);
        }
      }
  }
}

// ---------------- decoder ----------------
__global__ __launch_bounds__(128) void k_decoder(
    const float* __restrict__ h, const float* __restrict__ W1,
    const float* __restrict__ b1, const float* __restrict__ W2,
    const float* __restrict__ b2, float* __restrict__ out)
{
  const int n = blockIdx.x;
  const int j = threadIdx.x;
  __shared__ float hs[128];
  __shared__ float z1s[128];
  hs[j] = h[(size_t)n * 128 + j];
  __syncthreads();
  float z = b1[j];
  for (int k = 0; k < 128; ++k) z = fmaf(hs[k], W1[k * 128 + j], z);
  z1s[j] = gelu_exact(z);
  __syncthreads();
  if (j < 4) {
    float o = b2[j];
    for (int k = 0; k < 128; ++k) o = fmaf(z1s[k], W2[k * 4 + j], o);
    out[n * 4 + j] = o;
  }
}

static inline char* align_up(char* p, size_t a) {
  return (char*)(((uintptr_t)p + (a - 1)) & ~(uintptr_t)(a - 1));
}

extern "C" void kernel_launch(void* const* d_in, const int* in_sizes, int n_in,
                              void* d_out, int out_size, void* d_ws, size_t ws_size,
                              hipStream_t stream) {
  const float* x     = (const float*)d_in[0];
  const int*   eidx  = (const int*)d_in[1];
  const float* ea    = (const float*)d_in[2];
  const float* encW  = (const float*)d_in[3];
  const float* encb  = (const float*)d_in[4];
  const float* encg  = (const float*)d_in[5];
  const float* encbt = (const float*)d_in[6];
  const float* eencW = (const float*)d_in[7];
  const float* eencb = (const float*)d_in[8];
  const float* eW1   = (const float*)d_in[9];
  const float* eb1   = (const float*)d_in[10];
  const float* eg1   = (const float*)d_in[11];
  const float* ebt1  = (const float*)d_in[12];
  const float* eW2   = (const float*)d_in[13];
  const float* eb2   = (const float*)d_in[14];
  const float* eg2   = (const float*)d_in[15];
  const float* ebt2  = (const float*)d_in[16];
  const float* nW1   = (const float*)d_in[17];
  const float* nb1   = (const float*)d_in[18];
  const float* ng1   = (const float*)d_in[19];
  const float* nbt1  = (const float*)d_in[20];
  const float* nW2   = (const float*)d_in[21];
  const float* nb2   = (const float*)d_in[22];
  const float* ng2   = (const float*)d_in[23];
  const float* nbt2  = (const float*)d_in[24];
  const float* dW1   = (const float*)d_in[25];
  const float* db1   = (const float*)d_in[26];
  const float* dW2   = (const float*)d_in[27];
  const float* db2   = (const float*)d_in[28];
  float* out = (float*)d_out;

  char* p = (char*)d_ws;
  float* h   = (float*)p; p += (size_t)NN * 128 * 4;
  int* cnt     = (int*)p; p += (size_t)NN * 4;
  int* rowptr  = (int*)p; p += (size_t)(NN + 1) * 4;
  int* fillp   = (int*)p; p += (size_t)NN * 4;
  int* edge_of = (int*)p; p += (size_t)EE * 4;
  p = align_up(p, 256);
  ushort_t* h_bf = (ushort_t*)p; p += (size_t)NN * 128 * 2;
  p = align_up(p, 256);
  ushort_t* e_bf = (ushort_t*)p; p += (size_t)EE * 128 * 2;
  p = align_up(p, 256);
  ushort_t* Hpre = (ushort_t*)p; p += (size_t)NN * 512 * 2;
  p = align_up(p, 256);
  ushort_t* eW1pk = (ushort_t*)p; p += (size_t)L_LAYERS * 12 * 256 * 32 * 2;
  p = align_up(p, 256);
  ushort_t* eW2pk = (ushort_t*)p; p += (size_t)L_LAYERS * 8 * 128 * 32 * 2;
  p = align_up(p, 256);
  ushort_t* nW1pk = (ushort_t*)p; p += (size_t)L_LAYERS * 8 * 256 * 32 * 2;
  p = align_up(p, 256);
  ushort_t* nW2pk = (ushort_t*)p; p += (size_t)L_LAYERS * 8 * 128 * 32 * 2;

  {
    int n1 = L_LAYERS * 384 * 256;
    k_pack_w<<<(n1 + 255) / 256, 256, 0, stream>>>(eW1, eW1pk, 384, 256, n1);
    int n2 = L_LAYERS * 256 * 128;
    k_pack_w<<<(n2 + 255) / 256, 256, 0, stream>>>(eW2, eW2pk, 256, 128, n2);
    int n3 = L_LAYERS * 256 * 256;
    k_pack_w<<<(n3 + 255) / 256, 256, 0, stream>>>(nW1, nW1pk, 256, 256, n3);
    int n4 = L_LAYERS * 256 * 128;
    k_pack_w<<<(n4 + 255) / 256, 256, 0, stream>>>(nW2, nW2pk, 256, 128, n4);
  }

  k_encoder<<<NN, 128, 0, stream>>>(x, encW, encb, encg, encbt, h, h_bf);
  k_edge_enc<<<(EE * 128) / 256, 256, 0, stream>>>(ea, eencW, eencb, e_bf);
  k_zero_cnt<<<(NN + 255) / 256, 256, 0, stream>>>(cnt);
  k_count<<<EE / 256, 256, 0, stream>>>(eidx, cnt);
  k_scan<<<1, 256, 0, stream>>>(cnt, rowptr, fillp);
  k_fill<<<EE / 256, 256, 0, stream>>>(eidx, fillp, edge_of);

  for (int l = 0; l < L_LAYERS; ++l) {
    k_hpre<<<(NN + 31) / 32, 512, 0, stream>>>(h_bf, eW1pk, eb1, Hpre, l);
    k_edge_mlp_mfma<<<EE / 32, 256, 0, stream>>>(Hpre, e_bf, eidx,
        eW1pk, eW2pk, eg1, ebt1, eb2, eg2, ebt2, l);
    k_node_mlp_mfma<<<(NN + 31) / 32, 256, 0, stream>>>(h, h_bf, e_bf, rowptr, edge_of,
        nW1pk, nW2pk, nb1, ng1, nbt1, nb2, ng2, nbt2, l);
  }
  k_decoder<<<NN, 128, 0, stream>>>(h, dW1, db1, dW2, db2, out);
}

// Round 13
// 1438.373 us; speedup vs baseline: 1.2966x; 1.0134x over previous
//
#include <hip/hip_runtime.h>

#define L_LAYERS 10
#define NN 10000
#define EE 160000

typedef unsigned short ushort_t;
typedef unsigned int uint_t;
typedef __attribute__((ext_vector_type(8))) short bf16x8;
typedef __attribute__((ext_vector_type(4))) float floatx4;

__device__ __forceinline__ ushort_t f2b(float f) {
  uint_t u = __float_as_uint(f);
  u += 0x7FFFu + ((u >> 16) & 1u);
  return (ushort_t)(u >> 16);
}
__device__ __forceinline__ float b2f(ushort_t v) {
  return __uint_as_float(((uint_t)v) << 16);
}
__device__ __forceinline__ uint_t pk2(float lo, float hi) {
  uint_t ul = __float_as_uint(lo), uh = __float_as_uint(hi);
  ul += 0x7FFFu + ((ul >> 16) & 1u);
  uh += 0x7FFFu + ((uh >> 16) & 1u);
  return (ul >> 16) | (uh & 0xFFFF0000u);
}
__device__ __forceinline__ float gelu_exact(float x) {
  return 0.5f * x * (1.0f + erff(x * 0.7071067811865475f));
}
// tanh-form GELU: x * sigmoid(1.5957691*(x + 0.044715 x^3))
__device__ __forceinline__ float gelu_fast(float x) {
  float x2 = x * x;
  float inner = fmaf(0.044715f * x2, x, x);
  float E = __expf(-1.5957691216f * inner);
  float R = __builtin_amdgcn_rcpf(1.0f + E);
  return x * R;
}
template <int CTRL>
__device__ __forceinline__ float dpp_addf(float x) {
  int y = __builtin_amdgcn_update_dpp(0, __float_as_int(x), CTRL, 0xF, 0xF, true);
  return x + __int_as_float(y);
}
__device__ __forceinline__ float row16_sum(float x) {
  x = dpp_addf<0xB1>(x);
  x = dpp_addf<0x4E>(x);
  x = dpp_addf<0x141>(x);
  x = dpp_addf<0x140>(x);
  return x;
}
#define MFMA16x32(a, b, c) __builtin_amdgcn_mfma_f32_16x16x32_bf16((a), (b), (c), 0, 0, 0)

// ---------------- weight pack: W[L][K][N] fp32 -> P[L][K/32][N][32] bf16 ----------------
__global__ __launch_bounds__(256) void k_pack_w(
    const float* __restrict__ W, ushort_t* __restrict__ P, int K, int N, int LKN)
{
  int idx = blockIdx.x * 256 + threadIdx.x;
  if (idx >= LKN) return;
  int n = idx % N;
  int t = idx / N;
  int k = t % K;
  int l = t / K;
  int ks = k >> 5, kk = k & 31;
  int Ks = K >> 5;
  P[(((size_t)((l * Ks + ks) * N + n)) << 5) + kk] = f2b(W[idx]);
}

// ---------------- encoder ----------------
__global__ __launch_bounds__(128) void k_encoder(
    const float* __restrict__ x, const float* __restrict__ W,
    const float* __restrict__ b, const float* __restrict__ g,
    const float* __restrict__ bt, float* __restrict__ h, ushort_t* __restrict__ h_bf)
{
  const int n = blockIdx.x;
  const int j = threadIdx.x;
  __shared__ float xs[7];
  __shared__ float red[4];
  if (j < 7) xs[j] = x[n * 7 + j];
  __syncthreads();
  float z = b[j];
  #pragma unroll
  for (int k = 0; k < 7; ++k) z = fmaf(xs[k], W[k * 128 + j], z);
  float sm = z, sq = z * z;
  #pragma unroll
  for (int off = 32; off > 0; off >>= 1) {
    sm += __shfl_down(sm, off);
    sq += __shfl_down(sq, off);
  }
  const int wv = j >> 6, ln = j & 63;
  if (ln == 0) { red[wv] = sm; red[2 + wv] = sq; }
  __syncthreads();
  float m = (red[0] + red[1]) * (1.0f / 128.0f);
  float var = (red[2] + red[3]) * (1.0f / 128.0f) - m * m;
  float zz = (z - m) * rsqrtf(var + 1e-5f) * g[j] + bt[j];
  float o = gelu_exact(zz);
  h[(size_t)n * 128 + j] = o;
  h_bf[(size_t)n * 128 + j] = f2b(o);
}

// ---------------- edge encoder (bf16-only e) ----------------
__global__ __launch_bounds__(256) void k_edge_enc(
    const float* __restrict__ ea, const float* __restrict__ W,
    const float* __restrict__ b, ushort_t* __restrict__ e_bf)
{
  const int i = blockIdx.x * 256 + threadIdx.x;
  const int eid = i >> 7, j = i & 127;
  float z = b[j];
  #pragma unroll
  for (int k = 0; k < 8; ++k) z = fmaf(ea[eid * 8 + k], W[k * 128 + j], z);
  e_bf[i] = f2b(z);
}

// ---------------- CSR build ----------------
__global__ void k_zero_cnt(int* __restrict__ cnt) {
  int i = blockIdx.x * 256 + threadIdx.x;
  if (i < NN) cnt[i] = 0;
}
__global__ void k_count(const int* __restrict__ eidx, int* __restrict__ cnt) {
  int i = blockIdx.x * 256 + threadIdx.x;
  atomicAdd(&cnt[eidx[EE + i]], 1);
}
__global__ __launch_bounds__(256) void k_scan(
    const int* __restrict__ cnt, int* __restrict__ rowptr, int* __restrict__ fillp)
{
  __shared__ int tot[256];
  __shared__ int off[257];
  const int t = threadIdx.x;
  const int C = 40;
  int s = 0;
  int lo = t * C, hi = lo + C; if (hi > NN) hi = NN;
  for (int i = lo; i < hi; ++i) s += cnt[i];
  tot[t] = s;
  __syncthreads();
  if (t == 0) {
    int r = 0;
    for (int i = 0; i < 256; ++i) { off[i] = r; r += tot[i]; }
    off[256] = r;
  }
  __syncthreads();
  int r = off[t];
  for (int i = lo; i < hi; ++i) {
    rowptr[i] = r; fillp[i] = r;
    r += cnt[i];
  }
  if (t == 0) rowptr[NN] = off[256];
}
__global__ void k_fill(const int* __restrict__ eidx, int* __restrict__ fillp,
                       int* __restrict__ edge_of) {
  int i = blockIdx.x * 256 + threadIdx.x;
  int c = eidx[EE + i];
  int pos = atomicAdd(&fillp[c], 1);
  edge_of[pos] = i;
}

// ---------------- Hpre (standalone, layer 0 only): bf16, C-fragment permuted ----------------
// Hpre[n][block*64 + ln15*4 + ni]: block<4 -> (h@W1a + b1), block>=4 -> (h@W1b)
__global__ __launch_bounds__(512) void k_hpre(
    const ushort_t* __restrict__ h_bf, const ushort_t* __restrict__ W1pk,
    const float* __restrict__ b1, ushort_t* __restrict__ Hpre, int layer)
{
  __shared__ __align__(16) ushort_t A16[32 * 136];
  const int tid = threadIdx.x;
  const int base = blockIdx.x * 32;
  const ushort_t* W1p = W1pk + (size_t)layer * (12 * 256 * 32);
  const float* b1p = b1 + layer * 256;

  {
    const int ei = tid >> 4, c = tid & 15;
    const int g = base + ei;
    uint4 v = {0u, 0u, 0u, 0u};
    if (g < NN) v = *(const uint4*)(h_bf + (size_t)g * 128 + c * 8);
    *(uint4*)&A16[ei * 136 + c * 8] = v;
  }
  __syncthreads();

  const int lane = tid & 63;
  const int wv = tid >> 6;        // 0..7
  const int ln15 = lane & 15;
  const int quad = lane >> 4;

  const int g0 = wv * 64;
  const int ksb = (g0 < 256) ? 0 : 4;
  const int ncol = (g0 < 256) ? g0 : (g0 - 256);

  floatx4 acc[2][4];
  #pragma unroll
  for (int mi = 0; mi < 2; ++mi)
    #pragma unroll
    for (int ni = 0; ni < 4; ++ni) acc[mi][ni] = (floatx4){0.f, 0.f, 0.f, 0.f};

  for (int ks = 0; ks < 4; ++ks) {
    bf16x8 a0 = *(const bf16x8*)&A16[ln15 * 136 + ks * 32 + quad * 8];
    bf16x8 a1 = *(const bf16x8*)&A16[(16 + ln15) * 136 + ks * 32 + quad * 8];
    #pragma unroll
    for (int ni = 0; ni < 4; ++ni) {
      bf16x8 b = *(const bf16x8*)&W1p[((size_t)((ksb + ks) * 256 + ncol + ni * 16 + ln15) << 5) + quad * 8];
      acc[0][ni] = MFMA16x32(a0, b, acc[0][ni]);
      acc[1][ni] = MFMA16x32(a1, b, acc[1][ni]);
    }
  }

  float bbv[4];
  #pragma unroll
  for (int ni = 0; ni < 4; ++ni)
    bbv[ni] = (g0 < 256) ? b1p[ncol + ni * 16 + ln15] : 0.0f;

  #pragma unroll
  for (int mi = 0; mi < 2; ++mi)
    #pragma unroll
    for (int r = 0; r < 4; ++r) {
      int row = mi * 16 + quad * 4 + r;
      int g = base + row;
      if (g < NN) {
        float v0 = acc[mi][0][r] + bbv[0];
        float v1 = acc[mi][1][r] + bbv[1];
        float v2 = acc[mi][2][r] + bbv[2];
        float v3 = acc[mi][3][r] + bbv[3];
        uint2 pv;
        pv.x = pk2(v0, v1);
        pv.y = pk2(v2, v3);
        *(uint2*)&Hpre[(size_t)g * 512 + g0 + ln15 * 4] = pv;
      }
    }
}

// ---------------- edge MLP (MFMA): 32 edges/block, 4 waves; e stored bf16-only ----------------
// Measured-best (r12: 88.5 us/dispatch). Unchanged.
__global__ __launch_bounds__(256) void k_edge_mlp_mfma(
    const ushort_t* __restrict__ Hpre, ushort_t* __restrict__ e_bf,
    const int* __restrict__ eidx,
    const ushort_t* __restrict__ W1pk, const ushort_t* __restrict__ W2pk,
    const float* __restrict__ g1, const float* __restrict__ bt1,
    const float* __restrict__ b2, const float* __restrict__ g2, const float* __restrict__ bt2,
    int layer)
{
  __shared__ __align__(16) ushort_t A16[32 * 136];   // e tile only
  __shared__ __align__(16) ushort_t Z16[32 * 264];
  __shared__ float red_s[32 * 4], red_q[32 * 4];
  __shared__ int s_row[32], s_col[32];

  const int tid = threadIdx.x;
  const int base = blockIdx.x * 32;
  const ushort_t* W1p = W1pk + (size_t)layer * (12 * 256 * 32);
  const ushort_t* W2p = W2pk + (size_t)layer * (8 * 128 * 32);
  const float* g1p = g1 + layer * 256;
  const float* bt1p = bt1 + layer * 256;
  const float* b2p = b2 + layer * 128;
  const float* g2p = g2 + layer * 128;
  const float* bt2p = bt2 + layer * 128;

  if (tid < 32) s_row[tid] = eidx[base + tid];
  else if (tid < 64) s_col[tid - 32] = eidx[EE + base + (tid - 32)];
  __syncthreads();

  // stage e (bf16): 32 edges x 16 chunks of 8 -> 2 chunks/thread
  #pragma unroll
  for (int i = 0; i < 2; ++i) {
    int idx = tid + i * 256;
    int ei = idx >> 4, c = idx & 15;
    *(uint4*)&A16[ei * 136 + c * 8] =
        *(const uint4*)(e_bf + (size_t)(base + ei) * 128 + c * 8);
  }
  __syncthreads();

  const int lane = tid & 63;
  const int wv = tid >> 6;
  const int ln15 = lane & 15;
  const int quad = lane >> 4;

  // ---- GEMM1 (K=128): [32x128] @ [128x256] using packed ks 8-11 ----
  floatx4 acc[2][4];
  #pragma unroll
  for (int mi = 0; mi < 2; ++mi)
    #pragma unroll
    for (int ni = 0; ni < 4; ++ni) acc[mi][ni] = (floatx4){0.f, 0.f, 0.f, 0.f};

  const int nb1 = wv * 64;
  for (int ks = 0; ks < 4; ++ks) {
    bf16x8 a0 = *(const bf16x8*)&A16[ln15 * 136 + ks * 32 + quad * 8];
    bf16x8 a1 = *(const bf16x8*)&A16[(16 + ln15) * 136 + ks * 32 + quad * 8];
    #pragma unroll
    for (int ni = 0; ni < 4; ++ni) {
      bf16x8 b = *(const bf16x8*)&W1p[((size_t)((8 + ks) * 256 + nb1 + ni * 16 + ln15) << 5) + quad * 8];
      acc[0][ni] = MFMA16x32(a0, b, acc[0][ni]);
      acc[1][ni] = MFMA16x32(a1, b, acc[1][ni]);
    }
  }

  // add Hpre gather (bf16, permuted): per row two contiguous 8B loads
  {
    const int po = nb1 + ln15 * 4;
    #pragma unroll
    for (int mi = 0; mi < 2; ++mi)
      #pragma unroll
      for (int r = 0; r < 4; ++r) {
        int row = mi * 16 + quad * 4 + r;
        uint2 vr = *(const uint2*)(Hpre + (size_t)s_row[row] * 512 + po);
        uint2 vc = *(const uint2*)(Hpre + (size_t)s_col[row] * 512 + 256 + po);
        acc[mi][0][r] += __uint_as_float(vr.x << 16) + __uint_as_float(vc.x << 16);
        acc[mi][1][r] += __uint_as_float(vr.x & 0xFFFF0000u) + __uint_as_float(vc.x & 0xFFFF0000u);
        acc[mi][2][r] += __uint_as_float(vr.y << 16) + __uint_as_float(vc.y << 16);
        acc[mi][3][r] += __uint_as_float(vr.y & 0xFFFF0000u) + __uint_as_float(vc.y & 0xFFFF0000u);
      }
  }

  // LN1 partials
  #pragma unroll
  for (int mi = 0; mi < 2; ++mi)
    #pragma unroll
    for (int r = 0; r < 4; ++r) {
      float v = 0.f, u = 0.f;
      #pragma unroll
      for (int ni = 0; ni < 4; ++ni) { float x = acc[mi][ni][r]; v += x; u += x * x; }
      v = row16_sum(v); u = row16_sum(u);
      if (ln15 == 0) {
        int row = mi * 16 + quad * 4 + r;
        red_s[row * 4 + wv] = v; red_q[row * 4 + wv] = u;
      }
    }
  __syncthreads();

  float mrow[2][4], rrow[2][4];
  #pragma unroll
  for (int mi = 0; mi < 2; ++mi)
    #pragma unroll
    for (int r = 0; r < 4; ++r) {
      int row = mi * 16 + quad * 4 + r;
      float S = red_s[row * 4] + red_s[row * 4 + 1] + red_s[row * 4 + 2] + red_s[row * 4 + 3];
      float Q = red_q[row * 4] + red_q[row * 4 + 1] + red_q[row * 4 + 2] + red_q[row * 4 + 3];
      float m = S * (1.f / 256.f);
      float var = Q * (1.f / 256.f) - m * m;
      mrow[mi][r] = m; rrow[mi][r] = rsqrtf(var + 1e-5f);
    }
  #pragma unroll
  for (int ni = 0; ni < 4; ++ni) {
    int col = nb1 + ni * 16 + ln15;
    float gg = g1p[col], bb = bt1p[col];
    #pragma unroll
    for (int mi = 0; mi < 2; ++mi)
      #pragma unroll
      for (int r = 0; r < 4; ++r) {
        int row = mi * 16 + quad * 4 + r;
        float z = (acc[mi][ni][r] - mrow[mi][r]) * rrow[mi][r] * gg + bb;
        Z16[row * 264 + col] = f2b(gelu_fast(z));
      }
  }
  __syncthreads();

  // ---- GEMM2: [32x256] @ [256x128], ks ping-pong B prefetch ----
  floatx4 c2[2][2];
  #pragma unroll
  for (int mi = 0; mi < 2; ++mi)
    #pragma unroll
    for (int ni = 0; ni < 2; ++ni) c2[mi][ni] = (floatx4){0.f, 0.f, 0.f, 0.f};

  const int nb2 = wv * 32;
  {
    const ushort_t* Wf = W2p + ((size_t)(nb2 + ln15) << 5) + quad * 8;
    bf16x8 bA[2], bB[2];
    #pragma unroll
    for (int ni = 0; ni < 2; ++ni) bA[ni] = *(const bf16x8*)(Wf + (size_t)ni * (16 << 5));
    #pragma unroll
    for (int ks = 0; ks < 8; ks += 2) {
      #pragma unroll
      for (int ni = 0; ni < 2; ++ni)
        bB[ni] = *(const bf16x8*)(Wf + (size_t)(ks + 1) * (128 << 5) + (size_t)ni * (16 << 5));
      {
        bf16x8 a0 = *(const bf16x8*)&Z16[ln15 * 264 + ks * 32 + quad * 8];
        bf16x8 a1 = *(const bf16x8*)&Z16[(16 + ln15) * 264 + ks * 32 + quad * 8];
        #pragma unroll
        for (int ni = 0; ni < 2; ++ni) {
          c2[0][ni] = MFMA16x32(a0, bA[ni], c2[0][ni]);
          c2[1][ni] = MFMA16x32(a1, bA[ni], c2[1][ni]);
        }
      }
      if (ks + 2 < 8) {
        #pragma unroll
        for (int ni = 0; ni < 2; ++ni)
          bA[ni] = *(const bf16x8*)(Wf + (size_t)(ks + 2) * (128 << 5) + (size_t)ni * (16 << 5));
      }
      {
        bf16x8 a0 = *(const bf16x8*)&Z16[ln15 * 264 + (ks + 1) * 32 + quad * 8];
        bf16x8 a1 = *(const bf16x8*)&Z16[(16 + ln15) * 264 + (ks + 1) * 32 + quad * 8];
        #pragma unroll
        for (int ni = 0; ni < 2; ++ni) {
          c2[0][ni] = MFMA16x32(a0, bB[ni], c2[0][ni]);
          c2[1][ni] = MFMA16x32(a1, bB[ni], c2[1][ni]);
        }
      }
    }
  }

  #pragma unroll
  for (int ni = 0; ni < 2; ++ni) {
    float bb = b2p[nb2 + ni * 16 + ln15];
    #pragma unroll
    for (int mi = 0; mi < 2; ++mi)
      #pragma unroll
      for (int r = 0; r < 4; ++r) c2[mi][ni][r] += bb;
  }
  #pragma unroll
  for (int mi = 0; mi < 2; ++mi)
    #pragma unroll
    for (int r = 0; r < 4; ++r) {
      float v = 0.f, u = 0.f;
      #pragma unroll
      for (int ni = 0; ni < 2; ++ni) { float x = c2[mi][ni][r]; v += x; u += x * x; }
      v = row16_sum(v); u = row16_sum(u);
      if (ln15 == 0) {
        int row = mi * 16 + quad * 4 + r;
        red_s[row * 4 + wv] = v; red_q[row * 4 + wv] = u;
      }
    }
  __syncthreads();

  #pragma unroll
  for (int mi = 0; mi < 2; ++mi)
    #pragma unroll
    for (int r = 0; r < 4; ++r) {
      int row = mi * 16 + quad * 4 + r;
      float S = red_s[row * 4] + red_s[row * 4 + 1] + red_s[row * 4 + 2] + red_s[row * 4 + 3];
      float Q = red_q[row * 4] + red_q[row * 4 + 1] + red_q[row * 4 + 2] + red_q[row * 4 + 3];
      float m = S * (1.f / 128.f);
      float var = Q * (1.f / 128.f) - m * m;
      mrow[mi][r] = m; rrow[mi][r] = rsqrtf(var + 1e-5f);
    }
  #pragma unroll
  for (int ni = 0; ni < 2; ++ni) {
    int col = nb2 + ni * 16 + ln15;
    float gg = g2p[col], bb = bt2p[col];
    #pragma unroll
    for (int mi = 0; mi < 2; ++mi)
      #pragma unroll
      for (int r = 0; r < 4; ++r) {
        int row = mi * 16 + quad * 4 + r;
        float z = (c2[mi][ni][r] - mrow[mi][r]) * rrow[mi][r] * gg + bb;
        size_t gi = (size_t)(base + row) * 128 + col;
        e_bf[gi] = f2b(b2f(e_bf[gi]) + z);
      }
  }
}

// ---------------- node MLP (MFMA, fused scatter-mean + fused next-layer Hpre) ----------------
// 32 nodes/block. After updating h, writes h_new (bf16, A-layout) back into LDS and
// computes Hpre for layer hl (edge-MLP h-terms) without a separate kernel launch.
__global__ __launch_bounds__(256) void k_node_mlp_mfma(
    float* __restrict__ h, ushort_t* __restrict__ h_bf, const ushort_t* __restrict__ e_bf,
    const int* __restrict__ rowptr, const int* __restrict__ edge_of,
    const ushort_t* __restrict__ W1pk, const ushort_t* __restrict__ W2pk,
    const float* __restrict__ b1, const float* __restrict__ g1, const float* __restrict__ bt1,
    const float* __restrict__ b2, const float* __restrict__ g2, const float* __restrict__ bt2,
    const ushort_t* __restrict__ eW1pk, const float* __restrict__ eb1,
    ushort_t* __restrict__ Hpre, int layer, int hl)
{
  __shared__ __align__(16) ushort_t A16[32 * 264];
  __shared__ float red_s[32 * 4], red_q[32 * 4];
  ushort_t* Z16 = A16;

  const int tid = threadIdx.x;
  const int base = blockIdx.x * 32;
  const ushort_t* W1p = W1pk + (size_t)layer * (8 * 256 * 32);
  const ushort_t* W2p = W2pk + (size_t)layer * (8 * 128 * 32);
  const float* b1p = b1 + layer * 256;
  const float* g1p = g1 + layer * 256;
  const float* bt1p = bt1 + layer * 256;
  const float* b2p = b2 + layer * 128;
  const float* g2p = g2 + layer * 128;
  const float* bt2p = bt2 + layer * 128;

  // staging: 8 threads/node; seg owns 16 cols of h and 16 cols of agg
  {
    const int node = tid >> 3, seg = tid & 7;
    const int g = base + node;
    if (g < NN) {
      *(uint4*)&A16[node * 264 + seg * 16] =
          *(const uint4*)(h_bf + (size_t)g * 128 + seg * 16);
      *(uint4*)&A16[node * 264 + seg * 16 + 8] =
          *(const uint4*)(h_bf + (size_t)g * 128 + seg * 16 + 8);
      const int s = rowptr[g], en = rowptr[g + 1];
      float a[16];
      #pragma unroll
      for (int q = 0; q < 16; ++q) a[q] = 0.f;
      for (int it = s; it < en; ++it) {
        const ushort_t* src = e_bf + (size_t)edge_of[it] * 128 + seg * 16;
        uint4 v0 = *(const uint4*)src;
        uint4 v1 = *(const uint4*)(src + 8);
        a[0] += __uint_as_float(v0.x << 16); a[1] += __uint_as_float(v0.x & 0xFFFF0000u);
        a[2] += __uint_as_float(v0.y << 16); a[3] += __uint_as_float(v0.y & 0xFFFF0000u);
        a[4] += __uint_as_float(v0.z << 16); a[5] += __uint_as_float(v0.z & 0xFFFF0000u);
        a[6] += __uint_as_float(v0.w << 16); a[7] += __uint_as_float(v0.w & 0xFFFF0000u);
        a[8]  += __uint_as_float(v1.x << 16); a[9]  += __uint_as_float(v1.x & 0xFFFF0000u);
        a[10] += __uint_as_float(v1.y << 16); a[11] += __uint_as_float(v1.y & 0xFFFF0000u);
        a[12] += __uint_as_float(v1.z << 16); a[13] += __uint_as_float(v1.z & 0xFFFF0000u);
        a[14] += __uint_as_float(v1.w << 16); a[15] += __uint_as_float(v1.w & 0xFFFF0000u);
      }
      int c = en - s;
      float inv = 1.0f / (float)(c > 0 ? c : 1);
      uint4 p0, p1;
      p0.x = pk2(a[0] * inv, a[1] * inv);  p0.y = pk2(a[2] * inv, a[3] * inv);
      p0.z = pk2(a[4] * inv, a[5] * inv);  p0.w = pk2(a[6] * inv, a[7] * inv);
      p1.x = pk2(a[8] * inv, a[9] * inv);  p1.y = pk2(a[10] * inv, a[11] * inv);
      p1.z = pk2(a[12] * inv, a[13] * inv); p1.w = pk2(a[14] * inv, a[15] * inv);
      *(uint4*)&A16[node * 264 + 128 + seg * 16] = p0;
      *(uint4*)&A16[node * 264 + 128 + seg * 16 + 8] = p1;
    } else {
      uint4 zz = {0u, 0u, 0u, 0u};
      *(uint4*)&A16[node * 264 + seg * 16] = zz;
      *(uint4*)&A16[node * 264 + seg * 16 + 8] = zz;
      *(uint4*)&A16[node * 264 + 128 + seg * 16] = zz;
      *(uint4*)&A16[node * 264 + 128 + seg * 16 + 8] = zz;
    }
  }
  __syncthreads();

  const int lane = tid & 63;
  const int wv = tid >> 6;
  const int ln15 = lane & 15;
  const int quad = lane >> 4;

  // ---- GEMM1: [32x256] @ [256x256]; wave: 2 m-tiles x 4 n-tiles ----
  floatx4 acc[2][4];
  #pragma unroll
  for (int mi = 0; mi < 2; ++mi)
    #pragma unroll
    for (int ni = 0; ni < 4; ++ni) acc[mi][ni] = (floatx4){0.f, 0.f, 0.f, 0.f};

  const int nb1 = wv * 64;
  for (int ks = 0; ks < 8; ++ks) {
    bf16x8 a0 = *(const bf16x8*)&A16[ln15 * 264 + ks * 32 + quad * 8];
    bf16x8 a1 = *(const bf16x8*)&A16[(16 + ln15) * 264 + ks * 32 + quad * 8];
    #pragma unroll
    for (int ni = 0; ni < 4; ++ni) {
      bf16x8 b = *(const bf16x8*)&W1p[((size_t)(ks * 256 + nb1 + ni * 16 + ln15) << 5) + quad * 8];
      acc[0][ni] = MFMA16x32(a0, b, acc[0][ni]);
      acc[1][ni] = MFMA16x32(a1, b, acc[1][ni]);
    }
  }

  #pragma unroll
  for (int ni = 0; ni < 4; ++ni) {
    float bb = b1p[nb1 + ni * 16 + ln15];
    #pragma unroll
    for (int mi = 0; mi < 2; ++mi)
      #pragma unroll
      for (int r = 0; r < 4; ++r) acc[mi][ni][r] += bb;
  }
  #pragma unroll
  for (int mi = 0; mi < 2; ++mi)
    #pragma unroll
    for (int r = 0; r < 4; ++r) {
      float v = 0.f, u = 0.f;
      #pragma unroll
      for (int ni = 0; ni < 4; ++ni) { float x = acc[mi][ni][r]; v += x; u += x * x; }
      v = row16_sum(v); u = row16_sum(u);
      if (ln15 == 0) {
        int row = mi * 16 + quad * 4 + r;
        red_s[row * 4 + wv] = v; red_q[row * 4 + wv] = u;
      }
    }
  __syncthreads();

  float mrow[2][4], rrow[2][4];
  #pragma unroll
  for (int mi = 0; mi < 2; ++mi)
    #pragma unroll
    for (int r = 0; r < 4; ++r) {
      int row = mi * 16 + quad * 4 + r;
      float S = red_s[row * 4] + red_s[row * 4 + 1] + red_s[row * 4 + 2] + red_s[row * 4 + 3];
      float Q = red_q[row * 4] + red_q[row * 4 + 1] + red_q[row * 4 + 2] + red_q[row * 4 + 3];
      float m = S * (1.f / 256.f);
      float var = Q * (1.f / 256.f) - m * m;
      mrow[mi][r] = m; rrow[mi][r] = rsqrtf(var + 1e-5f);
    }
  #pragma unroll
  for (int ni = 0; ni < 4; ++ni) {
    int col = nb1 + ni * 16 + ln15;
    float gg = g1p[col], bb = bt1p[col];
    #pragma unroll
    for (int mi = 0; mi < 2; ++mi)
      #pragma unroll
      for (int r = 0; r < 4; ++r) {
        int row = mi * 16 + quad * 4 + r;
        float z = (acc[mi][ni][r] - mrow[mi][r]) * rrow[mi][r] * gg + bb;
        Z16[row * 264 + col] = f2b(gelu_fast(z));
      }
  }
  __syncthreads();

  // ---- GEMM2: [32x256] @ [256x128]; wave: 2 m-tiles x 2 n-tiles ----
  floatx4 c2[2][2];
  #pragma unroll
  for (int mi = 0; mi < 2; ++mi)
    #pragma unroll
    for (int ni = 0; ni < 2; ++ni) c2[mi][ni] = (floatx4){0.f, 0.f, 0.f, 0.f};

  const int nb2 = wv * 32;
  for (int ks = 0; ks < 8; ++ks) {
    bf16x8 a0 = *(const bf16x8*)&Z16[ln15 * 264 + ks * 32 + quad * 8];
    bf16x8 a1 = *(const bf16x8*)&Z16[(16 + ln15) * 264 + ks * 32 + quad * 8];
    #pragma unroll
    for (int ni = 0; ni < 2; ++ni) {
      bf16x8 b = *(const bf16x8*)&W2p[((size_t)(ks * 128 + nb2 + ni * 16 + ln15) << 5) + quad * 8];
      c2[0][ni] = MFMA16x32(a0, b, c2[0][ni]);
      c2[1][ni] = MFMA16x32(a1, b, c2[1][ni]);
    }
  }

  #pragma unroll
  for (int ni = 0; ni < 2; ++ni) {
    float bb = b2p[nb2 + ni * 16 + ln15];
    #pragma unroll
    for (int mi = 0; mi < 2; ++mi)
      #pragma unroll
      for (int r = 0; r < 4; ++r) c2[mi][ni][r] += bb;
  }
  #pragma unroll
  for (int mi = 0; mi < 2; ++mi)
    #pragma unroll
    for (int r = 0; r < 4; ++r) {
      float v = 0.f, u = 0.f;
      #pragma unroll
      for (int ni = 0; ni < 2; ++ni) { float x = c2[mi][ni][r]; v += x; u += x * x; }
      v = row16_sum(v); u = row16_sum(u);
      if (ln15 == 0) {
        int row = mi * 16 + quad * 4 + r;
        red_s[row * 4 + wv] = v; red_q[row * 4 + wv] = u;
      }
    }
  __syncthreads();

  #pragma unroll
  for (int mi = 0; mi < 2; ++mi)
    #pragma unroll
    for (int r = 0; r < 4; ++r) {
      int row = mi * 16 + quad * 4 + r;
      float S = red_s[row * 4] + red_s[row * 4 + 1] + red_s[row * 4 + 2] + red_s[row * 4 + 3];
      float Q = red_q[row * 4] + red_q[row * 4 + 1] + red_q[row * 4 + 2] + red_q[row * 4 + 3];
      float m = S * (1.f / 128.f);
      float var = Q * (1.f / 128.f) - m * m;
      mrow[mi][r] = m; rrow[mi][r] = rsqrtf(var + 1e-5f);
    }
  // epilogue: update h (+ LDS copy of h_new in A-layout for the fused Hpre GEMM)
  #pragma unroll
  for (int ni = 0; ni < 2; ++ni) {
    int col = nb2 + ni * 16 + ln15;
    float gg = g2p[col], bb = bt2p[col];
    #pragma unroll
    for (int mi = 0; mi < 2; ++mi)
      #pragma unroll
      for (int r = 0; r < 4; ++r) {
        int row = mi * 16 + quad * 4 + r;
        int g = base + row;
        float nv = 0.f;
        if (g < NN) {
          float z = (c2[mi][ni][r] - mrow[mi][r]) * rrow[mi][r] * gg + bb;
          size_t gi = (size_t)g * 128 + col;
          nv = h[gi] + z;
          h[gi] = nv;
          h_bf[gi] = f2b(nv);
        }
        Z16[row * 264 + col] = f2b(nv);
      }
  }

  // ---- fused Hpre for layer hl (skip on last layer) ----
  if (hl >= 0) {
    __syncthreads();   // all h_new A-layout writes visible
    const ushort_t* hW1p = eW1pk + (size_t)hl * (12 * 256 * 32);
    const float* hb1p = eb1 + hl * 256;
    const int ncol = wv * 64;
    #pragma unroll
    for (int blk = 0; blk < 2; ++blk) {
      const int ksb = blk ? 4 : 0;
      const int g0 = blk ? (256 + ncol) : ncol;
      floatx4 ah[2][4];
      #pragma unroll
      for (int mi = 0; mi < 2; ++mi)
        #pragma unroll
        for (int ni = 0; ni < 4; ++ni) ah[mi][ni] = (floatx4){0.f, 0.f, 0.f, 0.f};
      for (int ks = 0; ks < 4; ++ks) {
        bf16x8 a0 = *(const bf16x8*)&Z16[ln15 * 264 + ks * 32 + quad * 8];
        bf16x8 a1 = *(const bf16x8*)&Z16[(16 + ln15) * 264 + ks * 32 + quad * 8];
        #pragma unroll
        for (int ni = 0; ni < 4; ++ni) {
          bf16x8 b = *(const bf16x8*)&hW1p[((size_t)((ksb + ks) * 256 + ncol + ni * 16 + ln15) << 5) + quad * 8];
          ah[0][ni] = MFMA16x32(a0, b, ah[0][ni]);
          ah[1][ni] = MFMA16x32(a1, b, ah[1][ni]);
        }
      }
      float bbv[4];
      #pragma unroll
      for (int ni = 0; ni < 4; ++ni)
        bbv[ni] = blk ? 0.0f : hb1p[ncol + ni * 16 + ln15];
      #pragma unroll
      for (int mi = 0; mi < 2; ++mi)
        #pragma unroll
        for (int r = 0; r < 4; ++r) {
          int row = mi * 16 + quad * 4 + r;
          int g = base + row;
          if (g < NN) {
            uint2 pv;
            pv.x = pk2(ah[mi][0][r] + bbv[0], ah[mi][1][r] + bbv[1]);
            pv.y = pk2(ah[mi][2][r] + bbv[2], ah[mi][3][r] + bbv[3]);
            *(uint2*)&Hpre[(size_t)g * 512 + g0 + ln15 * 4] = pv;
          }
        }
    }
  }
}

// ---------------- decoder ----------------
__global__ __launch_bounds__(128) void k_decoder(
    const float* __restrict__ h, const float* __restrict__ W1,
    const float* __restrict__ b1, const float* __restrict__ W2,
    const float* __restrict__ b2, float* __restrict__ out)
{
  const int n = blockIdx.x;
  const int j = threadIdx.x;
  __shared__ float hs[128];
  __shared__ float z1s[128];
  hs[j] = h[(size_t)n * 128 + j];
  __syncthreads();
  float z = b1[j];
  for (int k = 0; k < 128; ++k) z = fmaf(hs[k], W1[k * 128 + j], z);
  z1s[j] = gelu_exact(z);
  __syncthreads();
  if (j < 4) {
    float o = b2[j];
    for (int k = 0; k < 128; ++k) o = fmaf(z1s[k], W2[k * 4 + j], o);
    out[n * 4 + j] = o;
  }
}

static inline char* align_up(char* p, size_t a) {
  return (char*)(((uintptr_t)p + (a - 1)) & ~(uintptr_t)(a - 1));
}

extern "C" void kernel_launch(void* const* d_in, const int* in_sizes, int n_in,
                              void* d_out, int out_size, void* d_ws, size_t ws_size,
                              hipStream_t stream) {
  const float* x     = (const float*)d_in[0];
  const int*   eidx  = (const int*)d_in[1];
  const float* ea    = (const float*)d_in[2];
  const float* encW  = (const float*)d_in[3];
  const float* encb  = (const float*)d_in[4];
  const float* encg  = (const float*)d_in[5];
  const float* encbt = (const float*)d_in[6];
  const float* eencW = (const float*)d_in[7];
  const float* eencb = (const float*)d_in[8];
  const float* eW1   = (const float*)d_in[9];
  const float* eb1   = (const float*)d_in[10];
  const float* eg1   = (const float*)d_in[11];
  const float* ebt1  = (const float*)d_in[12];
  const float* eW2   = (const float*)d_in[13];
  const float* eb2   = (const float*)d_in[14];
  const float* eg2   = (const float*)d_in[15];
  const float* ebt2  = (const float*)d_in[16];
  const float* nW1   = (const float*)d_in[17];
  const float* nb1   = (const float*)d_in[18];
  const float* ng1   = (const float*)d_in[19];
  const float* nbt1  = (const float*)d_in[20];
  const float* nW2   = (const float*)d_in[21];
  const float* nb2   = (const float*)d_in[22];
  const float* ng2   = (const float*)d_in[23];
  const float* nbt2  = (const float*)d_in[24];
  const float* dW1   = (const float*)d_in[25];
  const float* db1   = (const float*)d_in[26];
  const float* dW2   = (const float*)d_in[27];
  const float* db2   = (const float*)d_in[28];
  float* out = (float*)d_out;

  char* p = (char*)d_ws;
  float* h   = (float*)p; p += (size_t)NN * 128 * 4;
  int* cnt     = (int*)p; p += (size_t)NN * 4;
  int* rowptr  = (int*)p; p += (size_t)(NN + 1) * 4;
  int* fillp   = (int*)p; p += (size_t)NN * 4;
  int* edge_of = (int*)p; p += (size_t)EE * 4;
  p = align_up(p, 256);
  ushort_t* h_bf = (ushort_t*)p; p += (size_t)NN * 128 * 2;
  p = align_up(p, 256);
  ushort_t* e_bf = (ushort_t*)p; p += (size_t)EE * 128 * 2;
  p = align_up(p, 256);
  ushort_t* Hpre = (ushort_t*)p; p += (size_t)NN * 512 * 2;
  p = align_up(p, 256);
  ushort_t* eW1pk = (ushort_t*)p; p += (size_t)L_LAYERS * 12 * 256 * 32 * 2;
  p = align_up(p, 256);
  ushort_t* eW2pk = (ushort_t*)p; p += (size_t)L_LAYERS * 8 * 128 * 32 * 2;
  p = align_up(p, 256);
  ushort_t* nW1pk = (ushort_t*)p; p += (size_t)L_LAYERS * 8 * 256 * 32 * 2;
  p = align_up(p, 256);
  ushort_t* nW2pk = (ushort_t*)p; p += (size_t)L_LAYERS * 8 * 128 * 32 * 2;

  {
    int n1 = L_LAYERS * 384 * 256;
    k_pack_w<<<(n1 + 255) / 256, 256, 0, stream>>>(eW1, eW1pk, 384, 256, n1);
    int n2 = L_LAYERS * 256 * 128;
    k_pack_w<<<(n2 + 255) / 256, 256, 0, stream>>>(eW2, eW2pk, 256, 128, n2);
    int n3 = L_LAYERS * 256 * 256;
    k_pack_w<<<(n3 + 255) / 256, 256, 0, stream>>>(nW1, nW1pk, 256, 256, n3);
    int n4 = L_LAYERS * 256 * 128;
    k_pack_w<<<(n4 + 255) / 256, 256, 0, stream>>>(nW2, nW2pk, 256, 128, n4);
  }

  k_encoder<<<NN, 128, 0, stream>>>(x, encW, encb, encg, encbt, h, h_bf);
  k_edge_enc<<<(EE * 128) / 256, 256, 0, stream>>>(ea, eencW, eencb, e_bf);
  k_zero_cnt<<<(NN + 255) / 256, 256, 0, stream>>>(cnt);
  k_count<<<EE / 256, 256, 0, stream>>>(eidx, cnt);
  k_scan<<<1, 256, 0, stream>>>(cnt, rowptr, fillp);
  k_fill<<<EE / 256, 256, 0, stream>>>(eidx, fillp, edge_of);

  // Hpre for layer 0 (from encoder output); subsequent layers fused into node kernel
  k_hpre<<<(NN + 31) / 32, 512, 0, stream>>>(h_bf, eW1pk, eb1, Hpre, 0);

  for (int l = 0; l < L_LAYERS; ++l) {
    k_edge_mlp_mfma<<<EE / 32, 256, 0, stream>>>(Hpre, e_bf, eidx,
        eW1pk, eW2pk, eg1, ebt1, eb2, eg2, ebt2, l);
    int hl = (l + 1 < L_LAYERS) ? (l + 1) : -1;
    k_node_mlp_mfma<<<(NN + 31) / 32, 256, 0, stream>>>(h, h_bf, e_bf, rowptr, edge_of,
        nW1pk, nW2pk, nb1, ng1, nbt1, nb2, ng2, nbt2,
        eW1pk, eb1, Hpre, l, hl);
  }
  k_decoder<<<NN, 128, 0, stream>>>(h, dW1, db1, dW2, db2, out);
}

// Round 14
// 1374.881 us; speedup vs baseline: 1.3564x; 1.0462x over previous
//
#include <hip/hip_runtime.h>

#define L_LAYERS 10
#define NN 10000
#define EE 160000

typedef unsigned short ushort_t;
typedef unsigned int uint_t;
typedef __attribute__((ext_vector_type(8))) short bf16x8;
typedef __attribute__((ext_vector_type(4))) float floatx4;

__device__ __forceinline__ ushort_t f2b(float f) {
  uint_t u = __float_as_uint(f);
  u += 0x7FFFu + ((u >> 16) & 1u);
  return (ushort_t)(u >> 16);
}
__device__ __forceinline__ float b2f(ushort_t v) {
  return __uint_as_float(((uint_t)v) << 16);
}
__device__ __forceinline__ uint_t pk2(float lo, float hi) {
  uint_t ul = __float_as_uint(lo), uh = __float_as_uint(hi);
  ul += 0x7FFFu + ((ul >> 16) & 1u);
  uh += 0x7FFFu + ((uh >> 16) & 1u);
  return (ul >> 16) | (uh & 0xFFFF0000u);
}
__device__ __forceinline__ float gelu_exact(float x) {
  return 0.5f * x * (1.0f + erff(x * 0.7071067811865475f));
}
// tanh-form GELU: x * sigmoid(1.5957691*(x + 0.044715 x^3))
__device__ __forceinline__ float gelu_fast(float x) {
  float x2 = x * x;
  float inner = fmaf(0.044715f * x2, x, x);
  float E = __expf(-1.5957691216f * inner);
  float R = __builtin_amdgcn_rcpf(1.0f + E);
  return x * R;
}
template <int CTRL>
__device__ __forceinline__ float dpp_addf(float x) {
  int y = __builtin_amdgcn_update_dpp(0, __float_as_int(x), CTRL, 0xF, 0xF, true);
  return x + __int_as_float(y);
}
__device__ __forceinline__ float row16_sum(float x) {
  x = dpp_addf<0xB1>(x);
  x = dpp_addf<0x4E>(x);
  x = dpp_addf<0x141>(x);
  x = dpp_addf<0x140>(x);
  return x;
}
#define MFMA16x32(a, b, c) __builtin_amdgcn_mfma_f32_16x16x32_bf16((a), (b), (c), 0, 0, 0)

// ---------------- weight pack: W[L][K][N] fp32 -> P[L][K/32][N][32] bf16 ----------------
__global__ __launch_bounds__(256) void k_pack_w(
    const float* __restrict__ W, ushort_t* __restrict__ P, int K, int N, int LKN)
{
  int idx = blockIdx.x * 256 + threadIdx.x;
  if (idx >= LKN) return;
  int n = idx % N;
  int t = idx / N;
  int k = t % K;
  int l = t / K;
  int ks = k >> 5, kk = k & 31;
  int Ks = K >> 5;
  P[(((size_t)((l * Ks + ks) * N + n)) << 5) + kk] = f2b(W[idx]);
}

// ---------------- encoder ----------------
__global__ __launch_bounds__(128) void k_encoder(
    const float* __restrict__ x, const float* __restrict__ W,
    const float* __restrict__ b, const float* __restrict__ g,
    const float* __restrict__ bt, float* __restrict__ h, ushort_t* __restrict__ h_bf)
{
  const int n = blockIdx.x;
  const int j = threadIdx.x;
  __shared__ float xs[7];
  __shared__ float red[4];
  if (j < 7) xs[j] = x[n * 7 + j];
  __syncthreads();
  float z = b[j];
  #pragma unroll
  for (int k = 0; k < 7; ++k) z = fmaf(xs[k], W[k * 128 + j], z);
  float sm = z, sq = z * z;
  #pragma unroll
  for (int off = 32; off > 0; off >>= 1) {
    sm += __shfl_down(sm, off);
    sq += __shfl_down(sq, off);
  }
  const int wv = j >> 6, ln = j & 63;
  if (ln == 0) { red[wv] = sm; red[2 + wv] = sq; }
  __syncthreads();
  float m = (red[0] + red[1]) * (1.0f / 128.0f);
  float var = (red[2] + red[3]) * (1.0f / 128.0f) - m * m;
  float zz = (z - m) * rsqrtf(var + 1e-5f) * g[j] + bt[j];
  float o = gelu_exact(zz);
  h[(size_t)n * 128 + j] = o;
  h_bf[(size_t)n * 128 + j] = f2b(o);
}

// ---------------- edge encoder (bf16-only e) ----------------
__global__ __launch_bounds__(256) void k_edge_enc(
    const float* __restrict__ ea, const float* __restrict__ W,
    const float* __restrict__ b, ushort_t* __restrict__ e_bf)
{
  const int i = blockIdx.x * 256 + threadIdx.x;
  const int eid = i >> 7, j = i & 127;
  float z = b[j];
  #pragma unroll
  for (int k = 0; k < 8; ++k) z = fmaf(ea[eid * 8 + k], W[k * 128 + j], z);
  e_bf[i] = f2b(z);
}

// ---------------- CSR build ----------------
__global__ void k_zero_cnt(int* __restrict__ cnt) {
  int i = blockIdx.x * 256 + threadIdx.x;
  if (i < NN) cnt[i] = 0;
}
__global__ void k_count(const int* __restrict__ eidx, int* __restrict__ cnt) {
  int i = blockIdx.x * 256 + threadIdx.x;
  atomicAdd(&cnt[eidx[EE + i]], 1);
}
__global__ __launch_bounds__(256) void k_scan(
    const int* __restrict__ cnt, int* __restrict__ rowptr, int* __restrict__ fillp)
{
  __shared__ int tot[256];
  __shared__ int off[257];
  const int t = threadIdx.x;
  const int C = 40;
  int s = 0;
  int lo = t * C, hi = lo + C; if (hi > NN) hi = NN;
  for (int i = lo; i < hi; ++i) s += cnt[i];
  tot[t] = s;
  __syncthreads();
  if (t == 0) {
    int r = 0;
    for (int i = 0; i < 256; ++i) { off[i] = r; r += tot[i]; }
    off[256] = r;
  }
  __syncthreads();
  int r = off[t];
  for (int i = lo; i < hi; ++i) {
    rowptr[i] = r; fillp[i] = r;
    r += cnt[i];
  }
  if (t == 0) rowptr[NN] = off[256];
}
__global__ void k_fill(const int* __restrict__ eidx, int* __restrict__ fillp,
                       int* __restrict__ edge_of) {
  int i = blockIdx.x * 256 + threadIdx.x;
  int c = eidx[EE + i];
  int pos = atomicAdd(&fillp[c], 1);
  edge_of[pos] = i;
}

// ---------------- Hpre (standalone, layer 0 only): bf16, C-fragment permuted ----------------
__global__ __launch_bounds__(512) void k_hpre(
    const ushort_t* __restrict__ h_bf, const ushort_t* __restrict__ W1pk,
    const float* __restrict__ b1, ushort_t* __restrict__ Hpre, int layer)
{
  __shared__ __align__(16) ushort_t A16[32 * 136];
  const int tid = threadIdx.x;
  const int base = blockIdx.x * 32;
  const ushort_t* W1p = W1pk + (size_t)layer * (12 * 256 * 32);
  const float* b1p = b1 + layer * 256;

  {
    const int ei = tid >> 4, c = tid & 15;
    const int g = base + ei;
    uint4 v = {0u, 0u, 0u, 0u};
    if (g < NN) v = *(const uint4*)(h_bf + (size_t)g * 128 + c * 8);
    *(uint4*)&A16[ei * 136 + c * 8] = v;
  }
  __syncthreads();

  const int lane = tid & 63;
  const int wv = tid >> 6;        // 0..7
  const int ln15 = lane & 15;
  const int quad = lane >> 4;

  const int g0 = wv * 64;
  const int ksb = (g0 < 256) ? 0 : 4;
  const int ncol = (g0 < 256) ? g0 : (g0 - 256);

  floatx4 acc[2][4];
  #pragma unroll
  for (int mi = 0; mi < 2; ++mi)
    #pragma unroll
    for (int ni = 0; ni < 4; ++ni) acc[mi][ni] = (floatx4){0.f, 0.f, 0.f, 0.f};

  for (int ks = 0; ks < 4; ++ks) {
    bf16x8 a0 = *(const bf16x8*)&A16[ln15 * 136 + ks * 32 + quad * 8];
    bf16x8 a1 = *(const bf16x8*)&A16[(16 + ln15) * 136 + ks * 32 + quad * 8];
    #pragma unroll
    for (int ni = 0; ni < 4; ++ni) {
      bf16x8 b = *(const bf16x8*)&W1p[((size_t)((ksb + ks) * 256 + ncol + ni * 16 + ln15) << 5) + quad * 8];
      acc[0][ni] = MFMA16x32(a0, b, acc[0][ni]);
      acc[1][ni] = MFMA16x32(a1, b, acc[1][ni]);
    }
  }

  float bbv[4];
  #pragma unroll
  for (int ni = 0; ni < 4; ++ni)
    bbv[ni] = (g0 < 256) ? b1p[ncol + ni * 16 + ln15] : 0.0f;

  #pragma unroll
  for (int mi = 0; mi < 2; ++mi)
    #pragma unroll
    for (int r = 0; r < 4; ++r) {
      int row = mi * 16 + quad * 4 + r;
      int g = base + row;
      if (g < NN) {
        uint2 pv;
        pv.x = pk2(acc[mi][0][r] + bbv[0], acc[mi][1][r] + bbv[1]);
        pv.y = pk2(acc[mi][2][r] + bbv[2], acc[mi][3][r] + bbv[3]);
        *(uint2*)&Hpre[(size_t)g * 512 + g0 + ln15 * 4] = pv;
      }
    }
}

// ---------------- edge MLP (MFMA): 32 edges/block, 4 waves; e stored bf16-only ----------------
// Measured-best (r12/r13: 88.4 us/dispatch). Unchanged.
__global__ __launch_bounds__(256) void k_edge_mlp_mfma(
    const ushort_t* __restrict__ Hpre, ushort_t* __restrict__ e_bf,
    const int* __restrict__ eidx,
    const ushort_t* __restrict__ W1pk, const ushort_t* __restrict__ W2pk,
    const float* __restrict__ g1, const float* __restrict__ bt1,
    const float* __restrict__ b2, const float* __restrict__ g2, const float* __restrict__ bt2,
    int layer)
{
  __shared__ __align__(16) ushort_t A16[32 * 136];   // e tile only
  __shared__ __align__(16) ushort_t Z16[32 * 264];
  __shared__ float red_s[32 * 4], red_q[32 * 4];
  __shared__ int s_row[32], s_col[32];

  const int tid = threadIdx.x;
  const int base = blockIdx.x * 32;
  const ushort_t* W1p = W1pk + (size_t)layer * (12 * 256 * 32);
  const ushort_t* W2p = W2pk + (size_t)layer * (8 * 128 * 32);
  const float* g1p = g1 + layer * 256;
  const float* bt1p = bt1 + layer * 256;
  const float* b2p = b2 + layer * 128;
  const float* g2p = g2 + layer * 128;
  const float* bt2p = bt2 + layer * 128;

  if (tid < 32) s_row[tid] = eidx[base + tid];
  else if (tid < 64) s_col[tid - 32] = eidx[EE + base + (tid - 32)];
  __syncthreads();

  // stage e (bf16): 32 edges x 16 chunks of 8 -> 2 chunks/thread
  #pragma unroll
  for (int i = 0; i < 2; ++i) {
    int idx = tid + i * 256;
    int ei = idx >> 4, c = idx & 15;
    *(uint4*)&A16[ei * 136 + c * 8] =
        *(const uint4*)(e_bf + (size_t)(base + ei) * 128 + c * 8);
  }
  __syncthreads();

  const int lane = tid & 63;
  const int wv = tid >> 6;
  const int ln15 = lane & 15;
  const int quad = lane >> 4;

  // ---- GEMM1 (K=128): [32x128] @ [128x256] using packed ks 8-11 ----
  floatx4 acc[2][4];
  #pragma unroll
  for (int mi = 0; mi < 2; ++mi)
    #pragma unroll
    for (int ni = 0; ni < 4; ++ni) acc[mi][ni] = (floatx4){0.f, 0.f, 0.f, 0.f};

  const int nb1 = wv * 64;
  for (int ks = 0; ks < 4; ++ks) {
    bf16x8 a0 = *(const bf16x8*)&A16[ln15 * 136 + ks * 32 + quad * 8];
    bf16x8 a1 = *(const bf16x8*)&A16[(16 + ln15) * 136 + ks * 32 + quad * 8];
    #pragma unroll
    for (int ni = 0; ni < 4; ++ni) {
      bf16x8 b = *(const bf16x8*)&W1p[((size_t)((8 + ks) * 256 + nb1 + ni * 16 + ln15) << 5) + quad * 8];
      acc[0][ni] = MFMA16x32(a0, b, acc[0][ni]);
      acc[1][ni] = MFMA16x32(a1, b, acc[1][ni]);
    }
  }

  // add Hpre gather (bf16, permuted): per row two contiguous 8B loads
  {
    const int po = nb1 + ln15 * 4;
    #pragma unroll
    for (int mi = 0; mi < 2; ++mi)
      #pragma unroll
      for (int r = 0; r < 4; ++r) {
        int row = mi * 16 + quad * 4 + r;
        uint2 vr = *(const uint2*)(Hpre + (size_t)s_row[row] * 512 + po);
        uint2 vc = *(const uint2*)(Hpre + (size_t)s_col[row] * 512 + 256 + po);
        acc[mi][0][r] += __uint_as_float(vr.x << 16) + __uint_as_float(vc.x << 16);
        acc[mi][1][r] += __uint_as_float(vr.x & 0xFFFF0000u) + __uint_as_float(vc.x & 0xFFFF0000u);
        acc[mi][2][r] += __uint_as_float(vr.y << 16) + __uint_as_float(vc.y << 16);
        acc[mi][3][r] += __uint_as_float(vr.y & 0xFFFF0000u) + __uint_as_float(vc.y & 0xFFFF0000u);
      }
  }

  // LN1 partials
  #pragma unroll
  for (int mi = 0; mi < 2; ++mi)
    #pragma unroll
    for (int r = 0; r < 4; ++r) {
      float v = 0.f, u = 0.f;
      #pragma unroll
      for (int ni = 0; ni < 4; ++ni) { float x = acc[mi][ni][r]; v += x; u += x * x; }
      v = row16_sum(v); u = row16_sum(u);
      if (ln15 == 0) {
        int row = mi * 16 + quad * 4 + r;
        red_s[row * 4 + wv] = v; red_q[row * 4 + wv] = u;
      }
    }
  __syncthreads();

  float mrow[2][4], rrow[2][4];
  #pragma unroll
  for (int mi = 0; mi < 2; ++mi)
    #pragma unroll
    for (int r = 0; r < 4; ++r) {
      int row = mi * 16 + quad * 4 + r;
      float S = red_s[row * 4] + red_s[row * 4 + 1] + red_s[row * 4 + 2] + red_s[row * 4 + 3];
      float Q = red_q[row * 4] + red_q[row * 4 + 1] + red_q[row * 4 + 2] + red_q[row * 4 + 3];
      float m = S * (1.f / 256.f);
      float var = Q * (1.f / 256.f) - m * m;
      mrow[mi][r] = m; rrow[mi][r] = rsqrtf(var + 1e-5f);
    }
  #pragma unroll
  for (int ni = 0; ni < 4; ++ni) {
    int col = nb1 + ni * 16 + ln15;
    float gg = g1p[col], bb = bt1p[col];
    #pragma unroll
    for (int mi = 0; mi < 2; ++mi)
      #pragma unroll
      for (int r = 0; r < 4; ++r) {
        int row = mi * 16 + quad * 4 + r;
        float z = (acc[mi][ni][r] - mrow[mi][r]) * rrow[mi][r] * gg + bb;
        Z16[row * 264 + col] = f2b(gelu_fast(z));
      }
  }
  __syncthreads();

  // ---- GEMM2: [32x256] @ [256x128], ks ping-pong B prefetch ----
  floatx4 c2[2][2];
  #pragma unroll
  for (int mi = 0; mi < 2; ++mi)
    #pragma unroll
    for (int ni = 0; ni < 2; ++ni) c2[mi][ni] = (floatx4){0.f, 0.f, 0.f, 0.f};

  const int nb2 = wv * 32;
  {
    const ushort_t* Wf = W2p + ((size_t)(nb2 + ln15) << 5) + quad * 8;
    bf16x8 bA[2], bB[2];
    #pragma unroll
    for (int ni = 0; ni < 2; ++ni) bA[ni] = *(const bf16x8*)(Wf + (size_t)ni * (16 << 5));
    #pragma unroll
    for (int ks = 0; ks < 8; ks += 2) {
      #pragma unroll
      for (int ni = 0; ni < 2; ++ni)
        bB[ni] = *(const bf16x8*)(Wf + (size_t)(ks + 1) * (128 << 5) + (size_t)ni * (16 << 5));
      {
        bf16x8 a0 = *(const bf16x8*)&Z16[ln15 * 264 + ks * 32 + quad * 8];
        bf16x8 a1 = *(const bf16x8*)&Z16[(16 + ln15) * 264 + ks * 32 + quad * 8];
        #pragma unroll
        for (int ni = 0; ni < 2; ++ni) {
          c2[0][ni] = MFMA16x32(a0, bA[ni], c2[0][ni]);
          c2[1][ni] = MFMA16x32(a1, bA[ni], c2[1][ni]);
        }
      }
      if (ks + 2 < 8) {
        #pragma unroll
        for (int ni = 0; ni < 2; ++ni)
          bA[ni] = *(const bf16x8*)(Wf + (size_t)(ks + 2) * (128 << 5) + (size_t)ni * (16 << 5));
      }
      {
        bf16x8 a0 = *(const bf16x8*)&Z16[ln15 * 264 + (ks + 1) * 32 + quad * 8];
        bf16x8 a1 = *(const bf16x8*)&Z16[(16 + ln15) * 264 + (ks + 1) * 32 + quad * 8];
        #pragma unroll
        for (int ni = 0; ni < 2; ++ni) {
          c2[0][ni] = MFMA16x32(a0, bB[ni], c2[0][ni]);
          c2[1][ni] = MFMA16x32(a1, bB[ni], c2[1][ni]);
        }
      }
    }
  }

  #pragma unroll
  for (int ni = 0; ni < 2; ++ni) {
    float bb = b2p[nb2 + ni * 16 + ln15];
    #pragma unroll
    for (int mi = 0; mi < 2; ++mi)
      #pragma unroll
      for (int r = 0; r < 4; ++r) c2[mi][ni][r] += bb;
  }
  #pragma unroll
  for (int mi = 0; mi < 2; ++mi)
    #pragma unroll
    for (int r = 0; r < 4; ++r) {
      float v = 0.f, u = 0.f;
      #pragma unroll
      for (int ni = 0; ni < 2; ++ni) { float x = c2[mi][ni][r]; v += x; u += x * x; }
      v = row16_sum(v); u = row16_sum(u);
      if (ln15 == 0) {
        int row = mi * 16 + quad * 4 + r;
        red_s[row * 4 + wv] = v; red_q[row * 4 + wv] = u;
      }
    }
  __syncthreads();

  #pragma unroll
  for (int mi = 0; mi < 2; ++mi)
    #pragma unroll
    for (int r = 0; r < 4; ++r) {
      int row = mi * 16 + quad * 4 + r;
      float S = red_s[row * 4] + red_s[row * 4 + 1] + red_s[row * 4 + 2] + red_s[row * 4 + 3];
      float Q = red_q[row * 4] + red_q[row * 4 + 1] + red_q[row * 4 + 2] + red_q[row * 4 + 3];
      float m = S * (1.f / 128.f);
      float var = Q * (1.f / 128.f) - m * m;
      mrow[mi][r] = m; rrow[mi][r] = rsqrtf(var + 1e-5f);
    }
  #pragma unroll
  for (int ni = 0; ni < 2; ++ni) {
    int col = nb2 + ni * 16 + ln15;
    float gg = g2p[col], bb = bt2p[col];
    #pragma unroll
    for (int mi = 0; mi < 2; ++mi)
      #pragma unroll
      for (int r = 0; r < 4; ++r) {
        int row = mi * 16 + quad * 4 + r;
        float z = (c2[mi][ni][r] - mrow[mi][r]) * rrow[mi][r] * gg + bb;
        size_t gi = (size_t)(base + row) * 128 + col;
        e_bf[gi] = f2b(b2f(e_bf[gi]) + z);
      }
  }
}

// ---------------- node MLP (MFMA, fused scatter-mean + fused next-layer Hpre) ----------------
// 16 nodes/block (625 blocks = NN/16 exactly, no bounds checks), 4 waves.
// After updating h, h_new (bf16, A-layout) goes back into LDS; fused Hpre GEMM follows.
__global__ __launch_bounds__(256) void k_node_mlp_mfma(
    float* __restrict__ h, ushort_t* __restrict__ h_bf, const ushort_t* __restrict__ e_bf,
    const int* __restrict__ rowptr, const int* __restrict__ edge_of,
    const ushort_t* __restrict__ W1pk, const ushort_t* __restrict__ W2pk,
    const float* __restrict__ b1, const float* __restrict__ g1, const float* __restrict__ bt1,
    const float* __restrict__ b2, const float* __restrict__ g2, const float* __restrict__ bt2,
    const ushort_t* __restrict__ eW1pk, const float* __restrict__ eb1,
    ushort_t* __restrict__ Hpre, int layer, int hl)
{
  __shared__ __align__(16) ushort_t A16[16 * 264];
  __shared__ float red_s[16 * 4], red_q[16 * 4];
  ushort_t* Z16 = A16;

  const int tid = threadIdx.x;
  const int base = blockIdx.x * 16;   // 625 * 16 = 10000 exactly
  const ushort_t* W1p = W1pk + (size_t)layer * (8 * 256 * 32);
  const ushort_t* W2p = W2pk + (size_t)layer * (8 * 128 * 32);
  const float* b1p = b1 + layer * 256;
  const float* g1p = g1 + layer * 256;
  const float* bt1p = bt1 + layer * 256;
  const float* b2p = b2 + layer * 128;
  const float* g2p = g2 + layer * 128;
  const float* bt2p = bt2 + layer * 128;

  // staging: 16 threads/node; seg owns 8 cols of h and 8 cols of agg
  {
    const int node = tid >> 4, seg = tid & 15;
    const int g = base + node;
    *(uint4*)&A16[node * 264 + seg * 8] = *(const uint4*)(h_bf + (size_t)g * 128 + seg * 8);
    const int s = rowptr[g], en = rowptr[g + 1];
    float a0 = 0.f, a1 = 0.f, a2 = 0.f, a3 = 0.f, a4 = 0.f, a5 = 0.f, a6 = 0.f, a7 = 0.f;
    for (int it = s; it < en; ++it) {
      uint4 v = *(const uint4*)(e_bf + (size_t)edge_of[it] * 128 + seg * 8);
      a0 += __uint_as_float(v.x << 16); a1 += __uint_as_float(v.x & 0xFFFF0000u);
      a2 += __uint_as_float(v.y << 16); a3 += __uint_as_float(v.y & 0xFFFF0000u);
      a4 += __uint_as_float(v.z << 16); a5 += __uint_as_float(v.z & 0xFFFF0000u);
      a6 += __uint_as_float(v.w << 16); a7 += __uint_as_float(v.w & 0xFFFF0000u);
    }
    int c = en - s;
    float inv = 1.0f / (float)(c > 0 ? c : 1);
    uint4 pv;
    pv.x = pk2(a0 * inv, a1 * inv);
    pv.y = pk2(a2 * inv, a3 * inv);
    pv.z = pk2(a4 * inv, a5 * inv);
    pv.w = pk2(a6 * inv, a7 * inv);
    *(uint4*)&A16[node * 264 + 128 + seg * 8] = pv;
  }
  __syncthreads();

  const int lane = tid & 63;
  const int wv = tid >> 6;
  const int ln15 = lane & 15;
  const int quad = lane >> 4;

  // ---- GEMM1: [16x256] @ [256x256]; wave: 1 m-tile x 4 n-tiles ----
  floatx4 acc[4];
  #pragma unroll
  for (int ni = 0; ni < 4; ++ni) acc[ni] = (floatx4){0.f, 0.f, 0.f, 0.f};

  const int nb1 = wv * 64;
  for (int ks = 0; ks < 8; ++ks) {
    bf16x8 a0 = *(const bf16x8*)&A16[ln15 * 264 + ks * 32 + quad * 8];
    #pragma unroll
    for (int ni = 0; ni < 4; ++ni) {
      bf16x8 b = *(const bf16x8*)&W1p[((size_t)(ks * 256 + nb1 + ni * 16 + ln15) << 5) + quad * 8];
      acc[ni] = MFMA16x32(a0, b, acc[ni]);
    }
  }

  #pragma unroll
  for (int ni = 0; ni < 4; ++ni) {
    float bb = b1p[nb1 + ni * 16 + ln15];
    #pragma unroll
    for (int r = 0; r < 4; ++r) acc[ni][r] += bb;
  }
  #pragma unroll
  for (int r = 0; r < 4; ++r) {
    float v = 0.f, u = 0.f;
    #pragma unroll
    for (int ni = 0; ni < 4; ++ni) { float x = acc[ni][r]; v += x; u += x * x; }
    v = row16_sum(v); u = row16_sum(u);
    if (ln15 == 0) {
      int row = quad * 4 + r;
      red_s[row * 4 + wv] = v; red_q[row * 4 + wv] = u;
    }
  }
  __syncthreads();

  float mrow[4], rrow[4];
  #pragma unroll
  for (int r = 0; r < 4; ++r) {
    int row = quad * 4 + r;
    float S = red_s[row * 4] + red_s[row * 4 + 1] + red_s[row * 4 + 2] + red_s[row * 4 + 3];
    float Q = red_q[row * 4] + red_q[row * 4 + 1] + red_q[row * 4 + 2] + red_q[row * 4 + 3];
    float m = S * (1.f / 256.f);
    float var = Q * (1.f / 256.f) - m * m;
    mrow[r] = m; rrow[r] = rsqrtf(var + 1e-5f);
  }
  #pragma unroll
  for (int ni = 0; ni < 4; ++ni) {
    int col = nb1 + ni * 16 + ln15;
    float gg = g1p[col], bb = bt1p[col];
    #pragma unroll
    for (int r = 0; r < 4; ++r) {
      int row = quad * 4 + r;
      float z = (acc[ni][r] - mrow[r]) * rrow[r] * gg + bb;
      Z16[row * 264 + col] = f2b(gelu_fast(z));
    }
  }
  __syncthreads();

  // ---- GEMM2: [16x256] @ [256x128]; wave: 1 m-tile x 2 n-tiles ----
  floatx4 c2[2];
  #pragma unroll
  for (int ni = 0; ni < 2; ++ni) c2[ni] = (floatx4){0.f, 0.f, 0.f, 0.f};

  const int nb2 = wv * 32;
  for (int ks = 0; ks < 8; ++ks) {
    bf16x8 a0 = *(const bf16x8*)&Z16[ln15 * 264 + ks * 32 + quad * 8];
    #pragma unroll
    for (int ni = 0; ni < 2; ++ni) {
      bf16x8 b = *(const bf16x8*)&W2p[((size_t)(ks * 128 + nb2 + ni * 16 + ln15) << 5) + quad * 8];
      c2[ni] = MFMA16x32(a0, b, c2[ni]);
    }
  }

  #pragma unroll
  for (int ni = 0; ni < 2; ++ni) {
    float bb = b2p[nb2 + ni * 16 + ln15];
    #pragma unroll
    for (int r = 0; r < 4; ++r) c2[ni][r] += bb;
  }
  #pragma unroll
  for (int r = 0; r < 4; ++r) {
    float v = 0.f, u = 0.f;
    #pragma unroll
    for (int ni = 0; ni < 2; ++ni) { float x = c2[ni][r]; v += x; u += x * x; }
    v = row16_sum(v); u = row16_sum(u);
    if (ln15 == 0) {
      int row = quad * 4 + r;
      red_s[row * 4 + wv] = v; red_q[row * 4 + wv] = u;
    }
  }
  __syncthreads();

  #pragma unroll
  for (int r = 0; r < 4; ++r) {
    int row = quad * 4 + r;
    float S = red_s[row * 4] + red_s[row * 4 + 1] + red_s[row * 4 + 2] + red_s[row * 4 + 3];
    float Q = red_q[row * 4] + red_q[row * 4 + 1] + red_q[row * 4 + 2] + red_q[row * 4 + 3];
    float m = S * (1.f / 128.f);
    float var = Q * (1.f / 128.f) - m * m;
    mrow[r] = m; rrow[r] = rsqrtf(var + 1e-5f);
  }
  // epilogue: update h (+ LDS copy of h_new in A-layout for the fused Hpre GEMM)
  #pragma unroll
  for (int ni = 0; ni < 2; ++ni) {
    int col = nb2 + ni * 16 + ln15;
    float gg = g2p[col], bb = bt2p[col];
    #pragma unroll
    for (int r = 0; r < 4; ++r) {
      int row = quad * 4 + r;
      int g = base + row;
      float z = (c2[ni][r] - mrow[r]) * rrow[r] * gg + bb;
      size_t gi = (size_t)g * 128 + col;
      float nv = h[gi] + z;
      h[gi] = nv;
      h_bf[gi] = f2b(nv);
      Z16[row * 264 + col] = f2b(nv);
    }
  }

  // ---- fused Hpre for layer hl (skip on last layer) ----
  if (hl >= 0) {
    __syncthreads();   // all h_new A-layout writes visible
    const ushort_t* hW1p = eW1pk + (size_t)hl * (12 * 256 * 32);
    const float* hb1p = eb1 + hl * 256;
    const int ncol = wv * 64;
    #pragma unroll
    for (int blk = 0; blk < 2; ++blk) {
      const int ksb = blk ? 4 : 0;
      const int g0 = blk ? (256 + ncol) : ncol;
      floatx4 ah[4];
      #pragma unroll
      for (int ni = 0; ni < 4; ++ni) ah[ni] = (floatx4){0.f, 0.f, 0.f, 0.f};
      for (int ks = 0; ks < 4; ++ks) {
        bf16x8 a0 = *(const bf16x8*)&Z16[ln15 * 264 + ks * 32 + quad * 8];
        #pragma unroll
        for (int ni = 0; ni < 4; ++ni) {
          bf16x8 b = *(const bf16x8*)&hW1p[((size_t)((ksb + ks) * 256 + ncol + ni * 16 + ln15) << 5) + quad * 8];
          ah[ni] = MFMA16x32(a0, b, ah[ni]);
        }
      }
      float bbv[4];
      #pragma unroll
      for (int ni = 0; ni < 4; ++ni)
        bbv[ni] = blk ? 0.0f : hb1p[ncol + ni * 16 + ln15];
      #pragma unroll
      for (int r = 0; r < 4; ++r) {
        int row = quad * 4 + r;
        int g = base + row;
        uint2 pv;
        pv.x = pk2(ah[0][r] + bbv[0], ah[1][r] + bbv[1]);
        pv.y = pk2(ah[2][r] + bbv[2], ah[3][r] + bbv[3]);
        *(uint2*)&Hpre[(size_t)g * 512 + g0 + ln15 * 4] = pv;
      }
    }
  }
}

// ---------------- decoder ----------------
__global__ __launch_bounds__(128) void k_decoder(
    const float* __restrict__ h, const float* __restrict__ W1,
    const float* __restrict__ b1, const float* __restrict__ W2,
    const float* __restrict__ b2, float* __restrict__ out)
{
  const int n = blockIdx.x;
  const int j = threadIdx.x;
  __shared__ float hs[128];
  __shared__ float z1s[128];
  hs[j] = h[(size_t)n * 128 + j];
  __syncthreads();
  float z = b1[j];
  for (int k = 0; k < 128; ++k) z = fmaf(hs[k], W1[k * 128 + j], z);
  z1s[j] = gelu_exact(z);
  __syncthreads();
  if (j < 4) {
    float o = b2[j];
    for (int k = 0; k < 128; ++k) o = fmaf(z1s[k], W2[k * 4 + j], o);
    out[n * 4 + j] = o;
  }
}

static inline char* align_up(char* p, size_t a) {
  return (char*)(((uintptr_t)p + (a - 1)) & ~(uintptr_t)(a - 1));
}

extern "C" void kernel_launch(void* const* d_in, const int* in_sizes, int n_in,
                              void* d_out, int out_size, void* d_ws, size_t ws_size,
                              hipStream_t stream) {
  const float* x     = (const float*)d_in[0];
  const int*   eidx  = (const int*)d_in[1];
  const float* ea    = (const float*)d_in[2];
  const float* encW  = (const float*)d_in[3];
  const float* encb  = (const float*)d_in[4];
  const float* encg  = (const float*)d_in[5];
  const float* encbt = (const float*)d_in[6];
  const float* eencW = (const float*)d_in[7];
  const float* eencb = (const float*)d_in[8];
  const float* eW1   = (const float*)d_in[9];
  const float* eb1   = (const float*)d_in[10];
  const float* eg1   = (const float*)d_in[11];
  const float* ebt1  = (const float*)d_in[12];
  const float* eW2   = (const float*)d_in[13];
  const float* eb2   = (const float*)d_in[14];
  const float* eg2   = (const float*)d_in[15];
  const float* ebt2  = (const float*)d_in[16];
  const float* nW1   = (const float*)d_in[17];
  const float* nb1   = (const float*)d_in[18];
  const float* ng1   = (const float*)d_in[19];
  const float* nbt1  = (const float*)d_in[20];
  const float* nW2   = (const float*)d_in[21];
  const float* nb2   = (const float*)d_in[22];
  const float* ng2   = (const float*)d_in[23];
  const float* nbt2  = (const float*)d_in[24];
  const float* dW1   = (const float*)d_in[25];
  const float* db1   = (const float*)d_in[26];
  const float* dW2   = (const float*)d_in[27];
  const float* db2   = (const float*)d_in[28];
  float* out = (float*)d_out;

  char* p = (char*)d_ws;
  float* h   = (float*)p; p += (size_t)NN * 128 * 4;
  int* cnt     = (int*)p; p += (size_t)NN * 4;
  int* rowptr  = (int*)p; p += (size_t)(NN + 1) * 4;
  int* fillp   = (int*)p; p += (size_t)NN * 4;
  int* edge_of = (int*)p; p += (size_t)EE * 4;
  p = align_up(p, 256);
  ushort_t* h_bf = (ushort_t*)p; p += (size_t)NN * 128 * 2;
  p = align_up(p, 256);
  ushort_t* e_bf = (ushort_t*)p; p += (size_t)EE * 128 * 2;
  p = align_up(p, 256);
  ushort_t* Hpre = (ushort_t*)p; p += (size_t)NN * 512 * 2;
  p = align_up(p, 256);
  ushort_t* eW1pk = (ushort_t*)p; p += (size_t)L_LAYERS * 12 * 256 * 32 * 2;
  p = align_up(p, 256);
  ushort_t* eW2pk = (ushort_t*)p; p += (size_t)L_LAYERS * 8 * 128 * 32 * 2;
  p = align_up(p, 256);
  ushort_t* nW1pk = (ushort_t*)p; p += (size_t)L_LAYERS * 8 * 256 * 32 * 2;
  p = align_up(p, 256);
  ushort_t* nW2pk = (ushort_t*)p; p += (size_t)L_LAYERS * 8 * 128 * 32 * 2;

  {
    int n1 = L_LAYERS * 384 * 256;
    k_pack_w<<<(n1 + 255) / 256, 256, 0, stream>>>(eW1, eW1pk, 384, 256, n1);
    int n2 = L_LAYERS * 256 * 128;
    k_pack_w<<<(n2 + 255) / 256, 256, 0, stream>>>(eW2, eW2pk, 256, 128, n2);
    int n3 = L_LAYERS * 256 * 256;
    k_pack_w<<<(n3 + 255) / 256, 256, 0, stream>>>(nW1, nW1pk, 256, 256, n3);
    int n4 = L_LAYERS * 256 * 128;
    k_pack_w<<<(n4 + 255) / 256, 256, 0, stream>>>(nW2, nW2pk, 256, 128, n4);
  }

  k_encoder<<<NN, 128, 0, stream>>>(x, encW, encb, encg, encbt, h, h_bf);
  k_edge_enc<<<(EE * 128) / 256, 256, 0, stream>>>(ea, eencW, eencb, e_bf);
  k_zero_cnt<<<(NN + 255) / 256, 256, 0, stream>>>(cnt);
  k_count<<<EE / 256, 256, 0, stream>>>(eidx, cnt);
  k_scan<<<1, 256, 0, stream>>>(cnt, rowptr, fillp);
  k_fill<<<EE / 256, 256, 0, stream>>>(eidx, fillp, edge_of);

  // Hpre for layer 0 (from encoder output); subsequent layers fused into node kernel
  k_hpre<<<(NN + 31) / 32, 512, 0, stream>>>(h_bf, eW1pk, eb1, Hpre, 0);

  for (int l = 0; l < L_LAYERS; ++l) {
    k_edge_mlp_mfma<<<EE / 32, 256, 0, stream>>>(Hpre, e_bf, eidx,
        eW1pk, eW2pk, eg1, ebt1, eb2, eg2, ebt2, l);
    int hl = (l + 1 < L_LAYERS) ? (l + 1) : -1;
    k_node_mlp_mfma<<<NN / 16, 256, 0, stream>>>(h, h_bf, e_bf, rowptr, edge_of,
        nW1pk, nW2pk, nb1, ng1, nbt1, nb2, ng2, nbt2,
        eW1pk, eb1, Hpre, l, hl);
  }
  k_decoder<<<NN, 128, 0, stream>>>(h, dW1, db1, dW2, db2, out);
}